// Round 14
// baseline (257.411 us; speedup 1.0000x reference)
//
#include <hip/hip_runtime.h>
#include <hip/hip_fp16.h>
#include <math.h>

#define SEQ    4096
#define DMODEL 1024

typedef _Float16 half8   __attribute__((ext_vector_type(8)));
typedef _Float16 half4v  __attribute__((ext_vector_type(4)));
typedef float    floatx4 __attribute__((ext_vector_type(4)));

__device__ inline void split_val(float v, _Float16& h, _Float16& l) {
    _Float16 hh = (_Float16)v;
    h = hh;
    l = (_Float16)(v - (float)hh);
}

// ---------------------------------------------------------------------------
// Fused prep (R13): blocks 0..3071 transpose wq/wk/wv (32x32 tiles) into
// hi/lo fp16; blocks 3072..4095 split x into hi/lo fp16.
// ---------------------------------------------------------------------------
__global__ __launch_bounds__(256) void prep(const float* __restrict__ x,
                                            const float* __restrict__ wq,
                                            const float* __restrict__ wk,
                                            const float* __restrict__ wv,
                                            _Float16* __restrict__ x_hi,
                                            _Float16* __restrict__ x_lo,
                                            _Float16* __restrict__ wqkT_hi,
                                            _Float16* __restrict__ wqkT_lo,
                                            _Float16* __restrict__ wvT) {
    __shared__ float tile[32][33];
    const int b = blockIdx.x;
    if (b < 3072) {
        const int which = b >> 10;           // 0=wq 1=wk 2=wv
        const int bb = b & 1023;
        const int c0 = (bb & 31) * 32;
        const int r0 = (bb >> 5) * 32;
        const float* w = (which == 0) ? wq : (which == 1) ? wk : wv;
        const int tx = threadIdx.x & 31, ty = threadIdx.x >> 5;
#pragma unroll
        for (int j = 0; j < 4; ++j)
            tile[ty * 4 + j][tx] = w[(size_t)(r0 + ty * 4 + j) * DMODEL + c0 + tx];
        __syncthreads();
        if (which < 2) {
            _Float16* th = wqkT_hi + (size_t)which * DMODEL * DMODEL;
            _Float16* tl = wqkT_lo + (size_t)which * DMODEL * DMODEL;
#pragma unroll
            for (int j = 0; j < 4; ++j) {
                float v = tile[tx][ty * 4 + j];
                size_t idx = (size_t)(c0 + ty * 4 + j) * DMODEL + r0 + tx;
                _Float16 h, l;
                split_val(v, h, l);
                th[idx] = h;
                tl[idx] = l;
            }
        } else {
#pragma unroll
            for (int j = 0; j < 4; ++j)
                wvT[(size_t)(c0 + ty * 4 + j) * DMODEL + r0 + tx] =
                    (_Float16)tile[tx][ty * 4 + j];
        }
    } else {
        const int t0 = (b - 3072) * 256 + threadIdx.x;
#pragma unroll
        for (int rep = 0; rep < 4; ++rep) {
            const size_t i = (size_t)t0 + (size_t)rep * 262144;
            floatx4 v = *(const floatx4*)(x + 4 * i);
            half4v h, l;
#pragma unroll
            for (int j = 0; j < 4; ++j) {
                _Float16 hh = (_Float16)v[j];
                _Float16 ll = (_Float16)(v[j] - (float)hh);
                h[j] = hh;
                l[j] = ll;
            }
            *(half4v*)(x_hi + 4 * i) = h;
            *(half4v*)(x_lo + 4 * i) = l;
        }
    }
}

// ---------------------------------------------------------------------------
// QK projection, consolidated 3-product (R13 exact — measured, fastest
// form): per real K-tile stage {A_hi, A_lo, B_hi, B_lo} (6 loads), 48 MFMA
// per window. Tile 128x256, BK=32, 32 K-tiles, 3-slot ring (144KB), gate
// vmcnt(6). Epilogue: fp16 hi -> Qh / Kh.
// ---------------------------------------------------------------------------
__global__ __launch_bounds__(512, 1) void gemm_qkproj_dp(
    const _Float16* __restrict__ Ahi, const _Float16* __restrict__ Alo,   // x_hi/x_lo [4096][1024]
    const _Float16* __restrict__ Bhi, const _Float16* __restrict__ Blo,   // wqkT_hi/lo [2048][1024]
    _Float16* __restrict__ Qh, _Float16* __restrict__ Kh) {
    __shared__ _Float16 Ah[3][128][32];   // 24 KB
    __shared__ _Float16 Al[3][128][32];   // 24 KB
    __shared__ _Float16 Bh[3][256][32];   // 48 KB
    __shared__ _Float16 Bl[3][256][32];   // 48 KB

    const int tid  = threadIdx.x;
    const int lane = tid & 63;
    const int wid  = tid >> 6;
    const int wm   = (wid >> 2) * 64;     // 0,64
    const int wn   = (wid & 3) * 64;      // 0,64,128,192

    const int rowA0 = blockIdx.y * 128;
    const int colB0 = blockIdx.x * 256;

    const int ar  = tid >> 2;             // 0..127
    const int ag  = tid & 3;
    const int ags = ag ^ ((ar >> 1) & 3);
    const char* aHiS = (const char*)(Ahi + (size_t)(rowA0 + ar) * DMODEL) + ags * 16;
    const char* aLoS = (const char*)(Alo + (size_t)(rowA0 + ar) * DMODEL) + ags * 16;
    const char* bHi0 = (const char*)(Bhi + (size_t)(colB0 + ar) * DMODEL) + ags * 16;
    const char* bHi1 = (const char*)(Bhi + (size_t)(colB0 + ar + 128) * DMODEL) + ags * 16;
    const char* bLo0 = (const char*)(Blo + (size_t)(colB0 + ar) * DMODEL) + ags * 16;
    const char* bLo1 = (const char*)(Blo + (size_t)(colB0 + ar + 128) * DMODEL) + ags * 16;

#define STAGE_Q(tt)                                                                  \
    do {                                                                             \
        const int _s = (tt) % 3;                                                     \
        const size_t _ko = (size_t)(tt) * 64;                                        \
        __builtin_amdgcn_global_load_lds(                                            \
            (const __attribute__((address_space(1))) void*)(aHiS + _ko),             \
            (__attribute__((address_space(3))) void*)&Ah[_s][ar][ag * 8], 16, 0, 0); \
        __builtin_amdgcn_global_load_lds(                                            \
            (const __attribute__((address_space(1))) void*)(aLoS + _ko),             \
            (__attribute__((address_space(3))) void*)&Al[_s][ar][ag * 8], 16, 0, 0); \
        __builtin_amdgcn_global_load_lds(                                            \
            (const __attribute__((address_space(1))) void*)(bHi0 + _ko),             \
            (__attribute__((address_space(3))) void*)&Bh[_s][ar][ag * 8], 16, 0, 0); \
        __builtin_amdgcn_global_load_lds(                                            \
            (const __attribute__((address_space(1))) void*)(bHi1 + _ko),             \
            (__attribute__((address_space(3))) void*)&Bh[_s][ar + 128][ag * 8], 16, 0, 0);\
        __builtin_amdgcn_global_load_lds(                                            \
            (const __attribute__((address_space(1))) void*)(bLo0 + _ko),             \
            (__attribute__((address_space(3))) void*)&Bl[_s][ar][ag * 8], 16, 0, 0); \
        __builtin_amdgcn_global_load_lds(                                            \
            (const __attribute__((address_space(1))) void*)(bLo1 + _ko),             \
            (__attribute__((address_space(3))) void*)&Bl[_s][ar + 128][ag * 8], 16, 0, 0);\
    } while (0)

    const int fm = lane & 15;
    const int fq = lane >> 4;
    const int ck = (fq ^ ((fm >> 1) & 3)) * 8;

    floatx4 acc[4][4] = {};

    auto tile_body = [&](int t, bool do_stage) {
        const int s = t % 3;
        half8 avh[4], avl[4], bvh[4], bvl[4];
#pragma unroll
        for (int i = 0; i < 4; ++i) {
            avh[i] = *(const half8*)&Ah[s][wm + i * 16 + fm][ck];
            avl[i] = *(const half8*)&Al[s][wm + i * 16 + fm][ck];
        }
#pragma unroll
        for (int j = 0; j < 4; ++j) {
            bvh[j] = *(const half8*)&Bh[s][wn + j * 16 + fm][ck];
            bvl[j] = *(const half8*)&Bl[s][wn + j * 16 + fm][ck];
        }
        if (do_stage) STAGE_Q(t + 2);
        asm volatile("" ::: "memory");
        __builtin_amdgcn_s_barrier();
        asm volatile("" ::: "memory");
        __builtin_amdgcn_s_setprio(1);
#pragma unroll
        for (int i = 0; i < 4; ++i)
#pragma unroll
            for (int j = 0; j < 4; ++j)
                acc[i][j] = __builtin_amdgcn_mfma_f32_16x16x32_f16(avh[i], bvh[j], acc[i][j], 0, 0, 0);
#pragma unroll
        for (int i = 0; i < 4; ++i)
#pragma unroll
            for (int j = 0; j < 4; ++j)
                acc[i][j] = __builtin_amdgcn_mfma_f32_16x16x32_f16(avh[i], bvl[j], acc[i][j], 0, 0, 0);
#pragma unroll
        for (int i = 0; i < 4; ++i)
#pragma unroll
            for (int j = 0; j < 4; ++j)
                acc[i][j] = __builtin_amdgcn_mfma_f32_16x16x32_f16(avl[i], bvh[j], acc[i][j], 0, 0, 0);
        __builtin_amdgcn_s_setprio(0);
    };

    // Prologue: stage tiles 0,1 (12 loads); vmcnt(6) -> tile 0 landed.
    STAGE_Q(0);
    STAGE_Q(1);
    asm volatile("s_waitcnt vmcnt(6)" ::: "memory");
    __builtin_amdgcn_s_barrier();
    asm volatile("" ::: "memory");

    // 32 K-tiles: t=0..29 stage t+2; peel 30 (drain 31), 31.
#pragma unroll 1
    for (int t = 0; t < 30; ++t) {
        tile_body(t, true);
        asm volatile("s_waitcnt vmcnt(6)" ::: "memory");
        __builtin_amdgcn_s_barrier();
        asm volatile("" ::: "memory");
    }
    tile_body(30, false);
    asm volatile("s_waitcnt vmcnt(0)" ::: "memory");
    __builtin_amdgcn_s_barrier();
    asm volatile("" ::: "memory");
    tile_body(31, false);
#undef STAGE_Q

    _Float16* dst = Qh;
    int cbase = colB0;
    if (colB0 >= 1024) { dst = Kh; cbase = colB0 - 1024; }

#pragma unroll
    for (int i = 0; i < 4; ++i) {
        const int growb = rowA0 + wm + i * 16 + fq * 4;
#pragma unroll
        for (int j = 0; j < 4; ++j) {
            const int gcol = wn + j * 16 + fm;
#pragma unroll
            for (int r = 0; r < 4; ++r)
                dst[(size_t)(growb + r) * DMODEL + cbase + gcol] =
                    (_Float16)acc[i][j][r];
        }
    }
}

// ---------------------------------------------------------------------------
// Score GEMM (R14): tile 256(M)x128(N) -> grid 512 blocks = 2 blocks/CU.
// R13 measured OccupancyPercent 20.5 = 1 block/CU (grid 256 on 256 CUs):
// the K-loop is small (K-halving saved only 9.3us of 71.7) — the ~60us
// fixed cost is fences + the heavy tile-softmax epilogue with ZERO
// co-resident work. 2 blocks/CU lets block A's epilogue overlap block B's
// loop (m114 inter-block overlap).
// 8 waves (4Mx2N), per-wave 64x64 (acc[4][4] = 64 regs, fits 128-reg/
// 4-wave-per-EU budget). 3-slot ring (72KB < 80KB for 2 blocks), 3 vmem/
// thread/tile, gate vmcnt(3) (prologue 0,1 gate 3 -> tile 0 landed; per
// tile stage t+2, fence vmcnt(3) -> t+1 landed; WAR slot (t-1)%3 closed at
// t-1's end barrier; peel 30/31 at vmcnt(0)). S = Qh @ Kh^T, K=1024.
// Tile-softmax epilogue: same 64-col span contract (wn in {0,64}).
// ---------------------------------------------------------------------------
__global__ __launch_bounds__(512, 4) void gemm_score_dp(
    const _Float16* __restrict__ Qh,   // [4096][1024]
    const _Float16* __restrict__ Kh,   // [4096][1024]
    _Float16* __restrict__ Ph, float* __restrict__ Marr, float* __restrict__ Larr,
    float scale) {
    __shared__ _Float16 As[3][256][32];   // 48 KB
    __shared__ _Float16 Bs[3][128][32];   // 24 KB

    const int tid  = threadIdx.x;
    const int lane = tid & 63;
    const int wid  = tid >> 6;
    const int wm   = (wid >> 1) * 64;     // 0,64,128,192
    const int wn   = (wid & 1) * 64;      // 0,64

    // XCD-aware bijective swizzle: nwg = 512 (grid 32 x 16), 512 = 8*64.
    const int lin = blockIdx.y * 32 + blockIdx.x;
    const int swz = (lin & 7) * 64 + (lin >> 3);
    const int rowA0 = (swz >> 5) * 256;
    const int colB0 = (swz & 31) * 128;

    // A staging: 1024 granules (256 rows x 4), 2 per thread (rows pr, pr+128).
    const int pr  = tid >> 2;
    const int pg  = tid & 3;
    const int pgs = pg ^ ((pr >> 1) & 3);
    const char* aSrc0 = (const char*)(Qh + (size_t)(rowA0 + pr) * DMODEL) + pgs * 16;
    const char* aSrc1 = (const char*)(Qh + (size_t)(rowA0 + pr + 128) * DMODEL) + pgs * 16;
    // B staging: 512 granules (128 rows x 4), 1 per thread.
    const char* bSrc0 = (const char*)(Kh + (size_t)(colB0 + pr) * DMODEL) + pgs * 16;

#define STAGE_S(t)                                                                  \
    do {                                                                            \
        const int _s = (t) % 3;                                                     \
        const size_t _ko = (size_t)(t) * 64;                                        \
        __builtin_amdgcn_global_load_lds(                                           \
            (const __attribute__((address_space(1))) void*)(aSrc0 + _ko),           \
            (__attribute__((address_space(3))) void*)&As[_s][pr][pg * 8], 16, 0, 0);\
        __builtin_amdgcn_global_load_lds(                                           \
            (const __attribute__((address_space(1))) void*)(aSrc1 + _ko),           \
            (__attribute__((address_space(3))) void*)&As[_s][pr + 128][pg * 8], 16, 0, 0);\
        __builtin_amdgcn_global_load_lds(                                           \
            (const __attribute__((address_space(1))) void*)(bSrc0 + _ko),           \
            (__attribute__((address_space(3))) void*)&Bs[_s][pr][pg * 8], 16, 0, 0);\
    } while (0)

    const int fm = lane & 15;
    const int fq = lane >> 4;
    const int ck = (fq ^ ((fm >> 1) & 3)) * 8;

    floatx4 acc[4][4] = {};

    auto tile_body = [&](int t, bool do_stage) {
        const int s = t % 3;
        half8 av[4], bv[4];
#pragma unroll
        for (int i = 0; i < 4; ++i) av[i] = *(const half8*)&As[s][wm + i * 16 + fm][ck];
#pragma unroll
        for (int j = 0; j < 4; ++j) bv[j] = *(const half8*)&Bs[s][wn + j * 16 + fm][ck];
        if (do_stage) STAGE_S(t + 2);
        asm volatile("" ::: "memory");
        __builtin_amdgcn_s_barrier();
        asm volatile("" ::: "memory");
        __builtin_amdgcn_s_setprio(1);
#pragma unroll
        for (int i = 0; i < 4; ++i)
#pragma unroll
            for (int j = 0; j < 4; ++j)
                acc[i][j] = __builtin_amdgcn_mfma_f32_16x16x32_f16(av[i], bv[j], acc[i][j], 0, 0, 0);
        __builtin_amdgcn_s_setprio(0);
    };

    // Prologue: stage tiles 0,1 (6 loads); vmcnt(3) -> tile 0 landed.
    STAGE_S(0);
    STAGE_S(1);
    asm volatile("s_waitcnt vmcnt(3)" ::: "memory");
    __builtin_amdgcn_s_barrier();
    asm volatile("" ::: "memory");

    // 32 K-tiles (K = 1024, BK = 32): t=0..29 stage t+2; peel 30/31.
#pragma unroll 1
    for (int t = 0; t < 30; ++t) {
        tile_body(t, true);
        asm volatile("s_waitcnt vmcnt(3)" ::: "memory");
        __builtin_amdgcn_s_barrier();
        asm volatile("" ::: "memory");
    }
    tile_body(30, false);
    asm volatile("s_waitcnt vmcnt(0)" ::: "memory");
    __builtin_amdgcn_s_barrier();
    asm volatile("" ::: "memory");
    tile_body(31, false);
#undef STAGE_S

    // ---- tile-softmax epilogue over this wave's 64x64 span ----
    const int tprime = (colB0 + wn) >> 6;
#pragma unroll
    for (int i = 0; i < 4; ++i) {
#pragma unroll
        for (int r = 0; r < 4; ++r) {
            const int grow = rowA0 + wm + i * 16 + fq * 4 + r;
            float s0 = acc[i][0][r] * scale;
            float s1 = acc[i][1][r] * scale;
            float s2 = acc[i][2][r] * scale;
            float s3 = acc[i][3][r] * scale;
            float mx = fmaxf(fmaxf(s0, s1), fmaxf(s2, s3));
            mx = fmaxf(mx, __shfl_xor(mx, 1));
            mx = fmaxf(mx, __shfl_xor(mx, 2));
            mx = fmaxf(mx, __shfl_xor(mx, 4));
            mx = fmaxf(mx, __shfl_xor(mx, 8));
            float p0 = __expf(s0 - mx);
            float p1 = __expf(s1 - mx);
            float p2 = __expf(s2 - mx);
            float p3 = __expf(s3 - mx);
            float sum = p0 + p1 + p2 + p3;
            sum += __shfl_xor(sum, 1);
            sum += __shfl_xor(sum, 2);
            sum += __shfl_xor(sum, 4);
            sum += __shfl_xor(sum, 8);
            _Float16* prow = Ph + (size_t)grow * SEQ + colB0 + wn + fm;
            prow[0]  = (_Float16)p0;
            prow[16] = (_Float16)p1;
            prow[32] = (_Float16)p2;
            prow[48] = (_Float16)p3;
            if (fm == 0) {
                Marr[(size_t)grow * 64 + tprime] = mx;
                Larr[(size_t)grow * 64 + tprime] = sum;
            }
        }
    }
}

// ---------------------------------------------------------------------------
// compute_c, coalesced: 64 rows per block (grid 64, 256 threads = 4 waves).
// ---------------------------------------------------------------------------
__global__ __launch_bounds__(256) void compute_c(const float* __restrict__ Marr,
                                                 const float* __restrict__ Larr,
                                                 _Float16* __restrict__ CarrT) {
    __shared__ float c_s[64][65];
    const int row0 = blockIdx.x * 64;
    const int wv = threadIdx.x >> 6;
    const int ln = threadIdx.x & 63;

#pragma unroll
    for (int k = 0; k < 16; ++k) {
        const int r = wv * 16 + k;
        float mt = Marr[(size_t)(row0 + r) * 64 + ln];
        float lt = Larr[(size_t)(row0 + r) * 64 + ln];
        float m = mt;
#pragma unroll
        for (int off = 32; off > 0; off >>= 1) m = fmaxf(m, __shfl_xor(m, off));
        float e = __expf(mt - m);
        float L = lt * e;
#pragma unroll
        for (int off = 32; off > 0; off >>= 1) L += __shfl_xor(L, off);
        c_s[r][ln] = e / L;
    }
    __syncthreads();

#pragma unroll
    for (int k = 0; k < 16; ++k) {
        const int t = wv * 16 + k;
        CarrT[(size_t)t * SEQ + row0 + ln] = (_Float16)c_s[ln][t];
    }
}

// ---------------------------------------------------------------------------
// PV GEMM, merged single phase (R13 exact), softmax-finalize scale folded
// into A-fragments: out = sum_t c[row][t] * (P_t @ V_t). Tile 128x128,
// BK=64, 8 waves, 4-slot ring (128KB) + cT 16KB, 4 vmem/tile, gate vmcnt(8).
// ---------------------------------------------------------------------------
__global__ __launch_bounds__(512, 1) void gemm_pv_dp(
    const _Float16* __restrict__ P,      // [4096][4096] (unscaled exp)
    const _Float16* __restrict__ VT,     // [1024][4096]
    const _Float16* __restrict__ CarrT,  // [64][4096]
    float* __restrict__ out) {           // [4096][1024]
    __shared__ _Float16 As[4][128][64];   // 64 KB
    __shared__ _Float16 Bs[4][128][64];   // 64 KB
    __shared__ _Float16 cT[64][128];      // 16 KB

    const int tid  = threadIdx.x;
    const int lane = tid & 63;
    const int wid  = tid >> 6;
    const int wm   = (wid >> 2) * 64;     // 0,64
    const int wn   = (wid & 3) * 32;      // 0,32,64,96

    const int rowA0 = blockIdx.y * 128;
    const int colB0 = blockIdx.x * 128;

    // Preload this block's c slab: cT[t][r] = CarrT[t][rowA0+r].
    {
        int g = tid;
#pragma unroll
        for (int it = 0; it < 2; ++it, g += 512) {
            const int t  = g >> 4;
            const int r8 = (g & 15) * 8;
            *(half8*)&cT[t][r8] =
                *(const half8*)(CarrT + (size_t)t * SEQ + rowA0 + r8);
        }
    }
    __syncthreads();

    const int prow = tid >> 3;            // 0..63
    const int pgr  = tid & 7;
    const int ags  = pgr ^ (prow & 7);
    const char* aSrc0 = (const char*)(P  + (size_t)(rowA0 + prow) * SEQ) + ags * 16;
    const char* aSrc1 = (const char*)(P  + (size_t)(rowA0 + prow + 64) * SEQ) + ags * 16;
    const char* bSrc0 = (const char*)(VT + (size_t)(colB0 + prow) * SEQ) + ags * 16;
    const char* bSrc1 = (const char*)(VT + (size_t)(colB0 + prow + 64) * SEQ) + ags * 16;

#define STAGE_PA(tt)                                                                \
    do {                                                                            \
        const int _s = (tt) & 3;                                                    \
        const size_t _ko = (size_t)(tt) * 128;                                      \
        __builtin_amdgcn_global_load_lds(                                           \
            (const __attribute__((address_space(1))) void*)(aSrc0 + _ko),           \
            (__attribute__((address_space(3))) void*)&As[_s][prow][pgr * 8], 16, 0, 0);\
        __builtin_amdgcn_global_load_lds(                                           \
            (const __attribute__((address_space(1))) void*)(aSrc1 + _ko),           \
            (__attribute__((address_space(3))) void*)&As[_s][prow + 64][pgr * 8], 16, 0, 0);\
    } while (0)

#define STAGE_PB(tt)                                                                \
    do {                                                                            \
        const int _s = (tt) & 3;                                                    \
        const size_t _ko = (size_t)(tt) * 128;                                      \
        __builtin_amdgcn_global_load_lds(                                           \
            (const __attribute__((address_space(1))) void*)(bSrc0 + _ko),           \
            (__attribute__((address_space(3))) void*)&Bs[_s][prow][pgr * 8], 16, 0, 0);\
        __builtin_amdgcn_global_load_lds(                                           \
            (const __attribute__((address_space(1))) void*)(bSrc1 + _ko),           \
            (__attribute__((address_space(3))) void*)&Bs[_s][prow + 64][pgr * 8], 16, 0, 0);\
    } while (0)

    const int fm = lane & 15;
    const int fq = lane >> 4;
    const int ck0 = ((fq    ) ^ (fm & 7)) * 8;   // k-slice 0 (k0..k0+31)
    const int ck1 = ((fq + 4) ^ (fm & 7)) * 8;   // k-slice 1 (k0+32..k0+63)

    floatx4 acc[4][2] = {};

    auto tile_body = [&](int t, bool do_stage) {
        const int s = t & 3;
        half8 av[4], av2[4], bv[2], bv2[2];
        _Float16 cs[4];
#pragma unroll
        for (int i = 0; i < 4; ++i) {
            av[i]  = *(const half8*)&As[s][wm + i * 16 + fm][ck0];
            av2[i] = *(const half8*)&As[s][wm + i * 16 + fm][ck1];
            cs[i]  = cT[t][wm + i * 16 + fm];
        }
#pragma unroll
        for (int j = 0; j < 2; ++j) {
            bv[j]  = *(const half8*)&Bs[s][wn + j * 16 + fm][ck0];
            bv2[j] = *(const half8*)&Bs[s][wn + j * 16 + fm][ck1];
        }
#pragma unroll
        for (int i = 0; i < 4; ++i)
#pragma unroll
            for (int e = 0; e < 8; ++e) {
                av[i][e]  *= cs[i];
                av2[i][e] *= cs[i];
            }
        if (do_stage) { STAGE_PA(t + 3); STAGE_PB(t + 3); }
        asm volatile("" ::: "memory");
        __builtin_amdgcn_s_barrier();
        asm volatile("" ::: "memory");
        __builtin_amdgcn_s_setprio(1);
#pragma unroll
        for (int i = 0; i < 4; ++i)
#pragma unroll
            for (int j = 0; j < 2; ++j)
                acc[i][j] = __builtin_amdgcn_mfma_f32_16x16x32_f16(av[i], bv[j], acc[i][j], 0, 0, 0);
#pragma unroll
        for (int i = 0; i < 4; ++i)
#pragma unroll
            for (int j = 0; j < 2; ++j)
                acc[i][j] = __builtin_amdgcn_mfma_f32_16x16x32_f16(av2[i], bv2[j], acc[i][j], 0, 0, 0);
        __builtin_amdgcn_s_setprio(0);
    };

    STAGE_PA(0); STAGE_PB(0);
    STAGE_PA(1); STAGE_PB(1);
    STAGE_PA(2); STAGE_PB(2);
    asm volatile("s_waitcnt vmcnt(8)" ::: "memory");
    __builtin_amdgcn_s_barrier();
    asm volatile("" ::: "memory");

    // 64 K-tiles (K = 4096, BK = 64).
#pragma unroll 1
    for (int t = 0; t < 61; ++t) {
        tile_body(t, true);
        asm volatile("s_waitcnt vmcnt(8)" ::: "memory");
        __builtin_amdgcn_s_barrier();
        asm volatile("" ::: "memory");
    }
    tile_body(61, false);
    asm volatile("s_waitcnt vmcnt(4)" ::: "memory");
    __builtin_amdgcn_s_barrier();
    asm volatile("" ::: "memory");
    tile_body(62, false);
    asm volatile("s_waitcnt vmcnt(0)" ::: "memory");
    __builtin_amdgcn_s_barrier();
    asm volatile("" ::: "memory");
    tile_body(63, false);
#undef STAGE_PA
#undef STAGE_PB

#pragma unroll
    for (int i = 0; i < 4; ++i) {
        const int growb = rowA0 + wm + i * 16 + fq * 4;
#pragma unroll
        for (int j = 0; j < 2; ++j) {
            const int gcol = colB0 + wn + j * 16 + fm;
#pragma unroll
            for (int r = 0; r < 4; ++r)
                out[(size_t)(growb + r) * DMODEL + gcol] = acc[i][j][r];
        }
    }
}

// ---------------------------------------------------------------------------
// Plain fp16 MFMA GEMM, tile 128x64 (16x16x32): V-projection.
// ---------------------------------------------------------------------------
template <int OUT_HALF>
__global__ __launch_bounds__(256) void gemm_h16_n64(
    const _Float16* __restrict__ A, int lda,
    const _Float16* __restrict__ B, int ldb,
    float* __restrict__ Cf, _Float16* __restrict__ Ch,
    int N, int K) {
    __shared__ _Float16 Ah[128][32];
    __shared__ _Float16 Bh[64][32];

    const int tid = threadIdx.x;
    const int lane = tid & 63;
    const int w = tid >> 6;
    const int wm = (w >> 1) * 64;
    const int wn = (w & 1) * 32;

    const int rowA0 = blockIdx.y * 128;
    const int colB0 = blockIdx.x * 64;

    const int sr = lane >> 2;
    const int sc = lane & 3;
    const int ra0 = w * 32 + sr;
    const int ra1 = ra0 + 16;
    const int rb0 = w * 16 + sr;
    const int cga0 = sc ^ ((ra0 >> 1) & 3);
    const int cga1 = sc ^ ((ra1 >> 1) & 3);
    const int cgb0 = sc ^ ((rb0 >> 1) & 3);

    const char* gp[3];
    gp[0] = (const char*)(A + (size_t)(rowA0 + ra0) * lda) + cga0 * 16;
    gp[1] = (const char*)(A + (size_t)(rowA0 + ra1) * lda) + cga1 * 16;
    gp[2] = (const char*)(B + (size_t)(colB0 + rb0) * ldb) + cgb0 * 16;

    _Float16* lp[3] = {
        &Ah[w * 32][0], &Ah[w * 32 + 16][0],
        &Bh[w * 16][0],
    };

    const int fm = lane & 15;
    const int fq = lane >> 4;
    const int ck = ((fq ^ ((fm >> 1) & 3)) * 8);

    floatx4 acc[4][2] = {};

    for (int k0 = 0; k0 < K; k0 += 32) {
#pragma unroll
        for (int t = 0; t < 3; ++t)
            __builtin_amdgcn_global_load_lds(
                (const __attribute__((address_space(1))) void*)gp[t],
                (__attribute__((address_space(3))) void*)lp[t], 16, 0, 0);
#pragma unroll
        for (int t = 0; t < 3; ++t) gp[t] += 64;
        __syncthreads();

        half8 av[4], bv[2];
#pragma unroll
        for (int i = 0; i < 4; ++i)
            av[i] = *(const half8*)&Ah[wm + i * 16 + fm][ck];
#pragma unroll
        for (int j = 0; j < 2; ++j)
            bv[j] = *(const half8*)&Bh[wn + j * 16 + fm][ck];
#pragma unroll
        for (int i = 0; i < 4; ++i)
#pragma unroll
            for (int j = 0; j < 2; ++j)
                acc[i][j] = __builtin_amdgcn_mfma_f32_16x16x32_f16(av[i], bv[j], acc[i][j], 0, 0, 0);
        __syncthreads();
    }

#pragma unroll
    for (int i = 0; i < 4; ++i) {
        const int growb = rowA0 + wm + i * 16 + fq * 4;
#pragma unroll
        for (int j = 0; j < 2; ++j) {
            const int gcol = colB0 + wn + j * 16 + fm;
#pragma unroll
            for (int r = 0; r < 4; ++r) {
                float v = acc[i][j][r];
                size_t idx = (size_t)(growb + r) * N + gcol;
                if (OUT_HALF) Ch[idx] = (_Float16)v;
                else          Cf[idx] = v;
            }
        }
    }
}

// ---------------------------------------------------------------------------
// Workspace layout (104 MB used):
//  [0,32M)    P fp16 [4096][4096] (region reused: x_hi [0,8M), x_lo [8,16M),
//             wqkT_hi [16,20M), wqkT_lo [20,24M), wvT [24,26M) all dead
//             before the score kernel writes P)
//  [32,33M)   Marr fp32 [4096][64]   [33,34M) Larr fp32 [4096][64]
//  [34,34.5M) CarrT fp16 [64][4096]
//  [64,72M)   Qh fp16 [4096][1024]
//  [72,80M)   Kh fp16 [4096][1024]
//  [96,104M)  VT fp16 [1024][4096]
// ---------------------------------------------------------------------------
extern "C" void kernel_launch(void* const* d_in, const int* in_sizes, int n_in,
                              void* d_out, int out_size, void* d_ws, size_t ws_size,
                              hipStream_t stream) {
    const float* x  = (const float*)d_in[0];
    const float* wq = (const float*)d_in[1];
    const float* wk = (const float*)d_in[2];
    const float* wv = (const float*)d_in[3];
    float* out = (float*)d_out;

    char* base = (char*)d_ws;
    const size_t MB = 1u << 20;
    _Float16* P       = (_Float16*)base;               // [4096][4096]
    _Float16* x_hi    = (_Float16*)(base + 0 * MB);
    _Float16* x_lo    = (_Float16*)(base + 8 * MB);
    _Float16* wqkT_hi = (_Float16*)(base + 16 * MB);   // [2048][1024]
    _Float16* wqkT_lo = (_Float16*)(base + 20 * MB);
    _Float16* wvT     = (_Float16*)(base + 24 * MB);   // [1024][1024]
    float*    Marr    = (float*)(base + 32 * MB);
    float*    Larr    = (float*)(base + 33 * MB);
    _Float16* CarrT   = (_Float16*)(base + 34 * MB);   // [64][4096]
    _Float16* Qh      = (_Float16*)(base + 64 * MB);   // [4096][1024]
    _Float16* Kh      = (_Float16*)(base + 72 * MB);   // [4096][1024]
    _Float16* VT      = (_Float16*)(base + 96 * MB);   // [1024][4096]

    // 1) fused prep (hi/lo splits — 3-product needs them)
    prep<<<4096, 256, 0, stream>>>(x, wq, wk, wv, x_hi, x_lo, wqkT_hi, wqkT_lo, wvT);

    // 2) QK projection, consolidated 3-product (48 MFMA/window, 32 K-tiles)
    dim3 gqk(2048 / 256, SEQ / 128);   // (8,32) — XCD = col-panel
    gemm_qkproj_dp<<<gqk, dim3(512), 0, stream>>>(x_hi, x_lo, wqkT_hi, wqkT_lo,
                                                  Qh, Kh);
    // V^T = wv^T @ x^T, plain fp16, tile 128x64
    dim3 gvt(SEQ / 64, DMODEL / 128);  // (64,8)
    gemm_h16_n64<1><<<gvt, 256, 0, stream>>>(wvT, DMODEL, x_hi, DMODEL,
                                             nullptr, VT, SEQ, DMODEL);

    // 3) scores + tile-softmax, tile 256x128 -> 512 blocks = 2 blocks/CU
    dim3 gs(SEQ / 128, SEQ / 256);     // (32,16)
    gemm_score_dp<<<gs, dim3(512), 0, stream>>>(Qh, Kh, P, Marr, Larr,
                                                1.0f / 32.0f);

    // 4) finalize coefficients only (no P traffic), coalesced writes
    compute_c<<<SEQ / 64, 256, 0, stream>>>(Marr, Larr, CarrT);

    // 5) out = sum_t c_t * (P_t @ V_t), merged-phase ring
    dim3 gpv(DMODEL / 128, SEQ / 128); // (8,32) — XCD = col-panel
    gemm_pv_dp<<<gpv, dim3(512), 0, stream>>>(P, VT, CarrT, out);
}

// Round 15
// 255.579 us; speedup vs baseline: 1.0072x; 1.0072x over previous
//
#include <hip/hip_runtime.h>
#include <hip/hip_fp16.h>
#include <math.h>

#define SEQ    4096
#define DMODEL 1024

typedef _Float16 half8   __attribute__((ext_vector_type(8)));
typedef _Float16 half4v  __attribute__((ext_vector_type(4)));
typedef float    floatx4 __attribute__((ext_vector_type(4)));

__device__ inline void split_val(float v, _Float16& h, _Float16& l) {
    _Float16 hh = (_Float16)v;
    h = hh;
    l = (_Float16)(v - (float)hh);
}

// ---------------------------------------------------------------------------
// Fused prep (R13): blocks 0..3071 transpose wq/wk/wv (32x32 tiles) into
// hi/lo fp16; blocks 3072..4095 split x into hi/lo fp16.
// ---------------------------------------------------------------------------
__global__ __launch_bounds__(256) void prep(const float* __restrict__ x,
                                            const float* __restrict__ wq,
                                            const float* __restrict__ wk,
                                            const float* __restrict__ wv,
                                            _Float16* __restrict__ x_hi,
                                            _Float16* __restrict__ x_lo,
                                            _Float16* __restrict__ wqkT_hi,
                                            _Float16* __restrict__ wqkT_lo,
                                            _Float16* __restrict__ wvT) {
    __shared__ float tile[32][33];
    const int b = blockIdx.x;
    if (b < 3072) {
        const int which = b >> 10;           // 0=wq 1=wk 2=wv
        const int bb = b & 1023;
        const int c0 = (bb & 31) * 32;
        const int r0 = (bb >> 5) * 32;
        const float* w = (which == 0) ? wq : (which == 1) ? wk : wv;
        const int tx = threadIdx.x & 31, ty = threadIdx.x >> 5;
#pragma unroll
        for (int j = 0; j < 4; ++j)
            tile[ty * 4 + j][tx] = w[(size_t)(r0 + ty * 4 + j) * DMODEL + c0 + tx];
        __syncthreads();
        if (which < 2) {
            _Float16* th = wqkT_hi + (size_t)which * DMODEL * DMODEL;
            _Float16* tl = wqkT_lo + (size_t)which * DMODEL * DMODEL;
#pragma unroll
            for (int j = 0; j < 4; ++j) {
                float v = tile[tx][ty * 4 + j];
                size_t idx = (size_t)(c0 + ty * 4 + j) * DMODEL + r0 + tx;
                _Float16 h, l;
                split_val(v, h, l);
                th[idx] = h;
                tl[idx] = l;
            }
        } else {
#pragma unroll
            for (int j = 0; j < 4; ++j)
                wvT[(size_t)(c0 + ty * 4 + j) * DMODEL + r0 + tx] =
                    (_Float16)tile[tx][ty * 4 + j];
        }
    } else {
        const int t0 = (b - 3072) * 256 + threadIdx.x;
#pragma unroll
        for (int rep = 0; rep < 4; ++rep) {
            const size_t i = (size_t)t0 + (size_t)rep * 262144;
            floatx4 v = *(const floatx4*)(x + 4 * i);
            half4v h, l;
#pragma unroll
            for (int j = 0; j < 4; ++j) {
                _Float16 hh = (_Float16)v[j];
                _Float16 ll = (_Float16)(v[j] - (float)hh);
                h[j] = hh;
                l[j] = ll;
            }
            *(half4v*)(x_hi + 4 * i) = h;
            *(half4v*)(x_lo + 4 * i) = l;
        }
    }
}

// ---------------------------------------------------------------------------
// QK projection, consolidated 3-product (R13 exact — measured 55.9us,
// 922 TF = the ~37% structural plateau): per K-tile stage
// {A_hi, A_lo, B_hi, B_lo} (6 loads), 48 MFMA per window. Tile 128x256,
// BK=32, 32 K-tiles, 3-slot ring (144KB), gate vmcnt(6).
// ---------------------------------------------------------------------------
__global__ __launch_bounds__(512, 1) void gemm_qkproj_dp(
    const _Float16* __restrict__ Ahi, const _Float16* __restrict__ Alo,   // x_hi/x_lo [4096][1024]
    const _Float16* __restrict__ Bhi, const _Float16* __restrict__ Blo,   // wqkT_hi/lo [2048][1024]
    _Float16* __restrict__ Qh, _Float16* __restrict__ Kh) {
    __shared__ _Float16 Ah[3][128][32];   // 24 KB
    __shared__ _Float16 Al[3][128][32];   // 24 KB
    __shared__ _Float16 Bh[3][256][32];   // 48 KB
    __shared__ _Float16 Bl[3][256][32];   // 48 KB

    const int tid  = threadIdx.x;
    const int lane = tid & 63;
    const int wid  = tid >> 6;
    const int wm   = (wid >> 2) * 64;     // 0,64
    const int wn   = (wid & 3) * 64;      // 0,64,128,192

    const int rowA0 = blockIdx.y * 128;
    const int colB0 = blockIdx.x * 256;

    const int ar  = tid >> 2;             // 0..127
    const int ag  = tid & 3;
    const int ags = ag ^ ((ar >> 1) & 3);
    const char* aHiS = (const char*)(Ahi + (size_t)(rowA0 + ar) * DMODEL) + ags * 16;
    const char* aLoS = (const char*)(Alo + (size_t)(rowA0 + ar) * DMODEL) + ags * 16;
    const char* bHi0 = (const char*)(Bhi + (size_t)(colB0 + ar) * DMODEL) + ags * 16;
    const char* bHi1 = (const char*)(Bhi + (size_t)(colB0 + ar + 128) * DMODEL) + ags * 16;
    const char* bLo0 = (const char*)(Blo + (size_t)(colB0 + ar) * DMODEL) + ags * 16;
    const char* bLo1 = (const char*)(Blo + (size_t)(colB0 + ar + 128) * DMODEL) + ags * 16;

#define STAGE_Q(tt)                                                                  \
    do {                                                                             \
        const int _s = (tt) % 3;                                                     \
        const size_t _ko = (size_t)(tt) * 64;                                        \
        __builtin_amdgcn_global_load_lds(                                            \
            (const __attribute__((address_space(1))) void*)(aHiS + _ko),             \
            (__attribute__((address_space(3))) void*)&Ah[_s][ar][ag * 8], 16, 0, 0); \
        __builtin_amdgcn_global_load_lds(                                            \
            (const __attribute__((address_space(1))) void*)(aLoS + _ko),             \
            (__attribute__((address_space(3))) void*)&Al[_s][ar][ag * 8], 16, 0, 0); \
        __builtin_amdgcn_global_load_lds(                                            \
            (const __attribute__((address_space(1))) void*)(bHi0 + _ko),             \
            (__attribute__((address_space(3))) void*)&Bh[_s][ar][ag * 8], 16, 0, 0); \
        __builtin_amdgcn_global_load_lds(                                            \
            (const __attribute__((address_space(1))) void*)(bHi1 + _ko),             \
            (__attribute__((address_space(3))) void*)&Bh[_s][ar + 128][ag * 8], 16, 0, 0);\
        __builtin_amdgcn_global_load_lds(                                            \
            (const __attribute__((address_space(1))) void*)(bLo0 + _ko),             \
            (__attribute__((address_space(3))) void*)&Bl[_s][ar][ag * 8], 16, 0, 0); \
        __builtin_amdgcn_global_load_lds(                                            \
            (const __attribute__((address_space(1))) void*)(bLo1 + _ko),             \
            (__attribute__((address_space(3))) void*)&Bl[_s][ar + 128][ag * 8], 16, 0, 0);\
    } while (0)

    const int fm = lane & 15;
    const int fq = lane >> 4;
    const int ck = (fq ^ ((fm >> 1) & 3)) * 8;

    floatx4 acc[4][4] = {};

    auto tile_body = [&](int t, bool do_stage) {
        const int s = t % 3;
        half8 avh[4], avl[4], bvh[4], bvl[4];
#pragma unroll
        for (int i = 0; i < 4; ++i) {
            avh[i] = *(const half8*)&Ah[s][wm + i * 16 + fm][ck];
            avl[i] = *(const half8*)&Al[s][wm + i * 16 + fm][ck];
        }
#pragma unroll
        for (int j = 0; j < 4; ++j) {
            bvh[j] = *(const half8*)&Bh[s][wn + j * 16 + fm][ck];
            bvl[j] = *(const half8*)&Bl[s][wn + j * 16 + fm][ck];
        }
        if (do_stage) STAGE_Q(t + 2);
        asm volatile("" ::: "memory");
        __builtin_amdgcn_s_barrier();
        asm volatile("" ::: "memory");
        __builtin_amdgcn_s_setprio(1);
#pragma unroll
        for (int i = 0; i < 4; ++i)
#pragma unroll
            for (int j = 0; j < 4; ++j)
                acc[i][j] = __builtin_amdgcn_mfma_f32_16x16x32_f16(avh[i], bvh[j], acc[i][j], 0, 0, 0);
#pragma unroll
        for (int i = 0; i < 4; ++i)
#pragma unroll
            for (int j = 0; j < 4; ++j)
                acc[i][j] = __builtin_amdgcn_mfma_f32_16x16x32_f16(avh[i], bvl[j], acc[i][j], 0, 0, 0);
#pragma unroll
        for (int i = 0; i < 4; ++i)
#pragma unroll
            for (int j = 0; j < 4; ++j)
                acc[i][j] = __builtin_amdgcn_mfma_f32_16x16x32_f16(avl[i], bvh[j], acc[i][j], 0, 0, 0);
        __builtin_amdgcn_s_setprio(0);
    };

    STAGE_Q(0);
    STAGE_Q(1);
    asm volatile("s_waitcnt vmcnt(6)" ::: "memory");
    __builtin_amdgcn_s_barrier();
    asm volatile("" ::: "memory");

#pragma unroll 1
    for (int t = 0; t < 30; ++t) {
        tile_body(t, true);
        asm volatile("s_waitcnt vmcnt(6)" ::: "memory");
        __builtin_amdgcn_s_barrier();
        asm volatile("" ::: "memory");
    }
    tile_body(30, false);
    asm volatile("s_waitcnt vmcnt(0)" ::: "memory");
    __builtin_amdgcn_s_barrier();
    asm volatile("" ::: "memory");
    tile_body(31, false);
#undef STAGE_Q

    _Float16* dst = Qh;
    int cbase = colB0;
    if (colB0 >= 1024) { dst = Kh; cbase = colB0 - 1024; }

#pragma unroll
    for (int i = 0; i < 4; ++i) {
        const int growb = rowA0 + wm + i * 16 + fq * 4;
#pragma unroll
        for (int j = 0; j < 4; ++j) {
            const int gcol = wn + j * 16 + fm;
#pragma unroll
            for (int r = 0; r < 4; ++r)
                dst[(size_t)(growb + r) * DMODEL + cbase + gcol] =
                    (_Float16)acc[i][j][r];
        }
    }
}

// ---------------------------------------------------------------------------
// Score GEMM (R14 exact — per-dispatch <=55.8us): tile 256x128, grid 512
// blocks = 2 blocks/CU, 8 waves (4Mx2N), per-wave 64x64. 3-slot ring
// (72KB), 3 vmem/thread/tile, gate vmcnt(3). S = Qh @ Kh^T, K=1024.
// Tile-softmax epilogue (64-col spans).
// ---------------------------------------------------------------------------
__global__ __launch_bounds__(512, 4) void gemm_score_dp(
    const _Float16* __restrict__ Qh,   // [4096][1024]
    const _Float16* __restrict__ Kh,   // [4096][1024]
    _Float16* __restrict__ Ph, float* __restrict__ Marr, float* __restrict__ Larr,
    float scale) {
    __shared__ _Float16 As[3][256][32];   // 48 KB
    __shared__ _Float16 Bs[3][128][32];   // 24 KB

    const int tid  = threadIdx.x;
    const int lane = tid & 63;
    const int wid  = tid >> 6;
    const int wm   = (wid >> 1) * 64;     // 0,64,128,192
    const int wn   = (wid & 1) * 64;      // 0,64

    // XCD-aware bijective swizzle: nwg = 512 (grid 32 x 16), 512 = 8*64.
    const int lin = blockIdx.y * 32 + blockIdx.x;
    const int swz = (lin & 7) * 64 + (lin >> 3);
    const int rowA0 = (swz >> 5) * 256;
    const int colB0 = (swz & 31) * 128;

    const int pr  = tid >> 2;
    const int pg  = tid & 3;
    const int pgs = pg ^ ((pr >> 1) & 3);
    const char* aSrc0 = (const char*)(Qh + (size_t)(rowA0 + pr) * DMODEL) + pgs * 16;
    const char* aSrc1 = (const char*)(Qh + (size_t)(rowA0 + pr + 128) * DMODEL) + pgs * 16;
    const char* bSrc0 = (const char*)(Kh + (size_t)(colB0 + pr) * DMODEL) + pgs * 16;

#define STAGE_S(t)                                                                  \
    do {                                                                            \
        const int _s = (t) % 3;                                                     \
        const size_t _ko = (size_t)(t) * 64;                                        \
        __builtin_amdgcn_global_load_lds(                                           \
            (const __attribute__((address_space(1))) void*)(aSrc0 + _ko),           \
            (__attribute__((address_space(3))) void*)&As[_s][pr][pg * 8], 16, 0, 0);\
        __builtin_amdgcn_global_load_lds(                                           \
            (const __attribute__((address_space(1))) void*)(aSrc1 + _ko),           \
            (__attribute__((address_space(3))) void*)&As[_s][pr + 128][pg * 8], 16, 0, 0);\
        __builtin_amdgcn_global_load_lds(                                           \
            (const __attribute__((address_space(1))) void*)(bSrc0 + _ko),           \
            (__attribute__((address_space(3))) void*)&Bs[_s][pr][pg * 8], 16, 0, 0);\
    } while (0)

    const int fm = lane & 15;
    const int fq = lane >> 4;
    const int ck = (fq ^ ((fm >> 1) & 3)) * 8;

    floatx4 acc[4][4] = {};

    auto tile_body = [&](int t, bool do_stage) {
        const int s = t % 3;
        half8 av[4], bv[4];
#pragma unroll
        for (int i = 0; i < 4; ++i) av[i] = *(const half8*)&As[s][wm + i * 16 + fm][ck];
#pragma unroll
        for (int j = 0; j < 4; ++j) bv[j] = *(const half8*)&Bs[s][wn + j * 16 + fm][ck];
        if (do_stage) STAGE_S(t + 2);
        asm volatile("" ::: "memory");
        __builtin_amdgcn_s_barrier();
        asm volatile("" ::: "memory");
        __builtin_amdgcn_s_setprio(1);
#pragma unroll
        for (int i = 0; i < 4; ++i)
#pragma unroll
            for (int j = 0; j < 4; ++j)
                acc[i][j] = __builtin_amdgcn_mfma_f32_16x16x32_f16(av[i], bv[j], acc[i][j], 0, 0, 0);
        __builtin_amdgcn_s_setprio(0);
    };

    STAGE_S(0);
    STAGE_S(1);
    asm volatile("s_waitcnt vmcnt(3)" ::: "memory");
    __builtin_amdgcn_s_barrier();
    asm volatile("" ::: "memory");

#pragma unroll 1
    for (int t = 0; t < 30; ++t) {
        tile_body(t, true);
        asm volatile("s_waitcnt vmcnt(3)" ::: "memory");
        __builtin_amdgcn_s_barrier();
        asm volatile("" ::: "memory");
    }
    tile_body(30, false);
    asm volatile("s_waitcnt vmcnt(0)" ::: "memory");
    __builtin_amdgcn_s_barrier();
    asm volatile("" ::: "memory");
    tile_body(31, false);
#undef STAGE_S

    const int tprime = (colB0 + wn) >> 6;
#pragma unroll
    for (int i = 0; i < 4; ++i) {
#pragma unroll
        for (int r = 0; r < 4; ++r) {
            const int grow = rowA0 + wm + i * 16 + fq * 4 + r;
            float s0 = acc[i][0][r] * scale;
            float s1 = acc[i][1][r] * scale;
            float s2 = acc[i][2][r] * scale;
            float s3 = acc[i][3][r] * scale;
            float mx = fmaxf(fmaxf(s0, s1), fmaxf(s2, s3));
            mx = fmaxf(mx, __shfl_xor(mx, 1));
            mx = fmaxf(mx, __shfl_xor(mx, 2));
            mx = fmaxf(mx, __shfl_xor(mx, 4));
            mx = fmaxf(mx, __shfl_xor(mx, 8));
            float p0 = __expf(s0 - mx);
            float p1 = __expf(s1 - mx);
            float p2 = __expf(s2 - mx);
            float p3 = __expf(s3 - mx);
            float sum = p0 + p1 + p2 + p3;
            sum += __shfl_xor(sum, 1);
            sum += __shfl_xor(sum, 2);
            sum += __shfl_xor(sum, 4);
            sum += __shfl_xor(sum, 8);
            _Float16* prow = Ph + (size_t)grow * SEQ + colB0 + wn + fm;
            prow[0]  = (_Float16)p0;
            prow[16] = (_Float16)p1;
            prow[32] = (_Float16)p2;
            prow[48] = (_Float16)p3;
            if (fm == 0) {
                Marr[(size_t)grow * 64 + tprime] = mx;
                Larr[(size_t)grow * 64 + tprime] = sum;
            }
        }
    }
}

// ---------------------------------------------------------------------------
// compute_c, coalesced: 64 rows per block (grid 64, 256 threads = 4 waves).
// ---------------------------------------------------------------------------
__global__ __launch_bounds__(256) void compute_c(const float* __restrict__ Marr,
                                                 const float* __restrict__ Larr,
                                                 _Float16* __restrict__ CarrT) {
    __shared__ float c_s[64][65];
    const int row0 = blockIdx.x * 64;
    const int wv = threadIdx.x >> 6;
    const int ln = threadIdx.x & 63;

#pragma unroll
    for (int k = 0; k < 16; ++k) {
        const int r = wv * 16 + k;
        float mt = Marr[(size_t)(row0 + r) * 64 + ln];
        float lt = Larr[(size_t)(row0 + r) * 64 + ln];
        float m = mt;
#pragma unroll
        for (int off = 32; off > 0; off >>= 1) m = fmaxf(m, __shfl_xor(m, off));
        float e = __expf(mt - m);
        float L = lt * e;
#pragma unroll
        for (int off = 32; off > 0; off >>= 1) L += __shfl_xor(L, off);
        c_s[r][ln] = e / L;
    }
    __syncthreads();

#pragma unroll
    for (int k = 0; k < 16; ++k) {
        const int t = wv * 16 + k;
        CarrT[(size_t)t * SEQ + row0 + ln] = (_Float16)c_s[ln][t];
    }
}

// ---------------------------------------------------------------------------
// V^T projection, MODERNIZED (R15): VT[m][n] = sum_k wvT[m][k]*x_hi[n][k].
// Replaces the last old-style kernel (gemm_h16_n64<1>: 8 MFMA between 2
// barriers, 64 barrier crossings — the window-density disease R12/R13
// cured in qkproj). Tile 128(M)x64(N), BK=32, 256 threads (4 waves, 2Mx2N,
// per-wave 64x32), 3-slot ring (36KB -> well under 2-blocks/CU budget;
// grid 512 = 2 blocks/CU), 3 vmem/thread/tile, gate vmcnt(3), prefetch
// distance 2 (prologue 0,1 gate 3 -> tile 0 landed; stage t+2, fence
// vmcnt(3) -> t+1 landed; WAR slot (t-1)%3 closed at t-1's barrier; peel
// 30/31 at vmcnt(0)). Same products/order as the old kernel.
// ---------------------------------------------------------------------------
__global__ __launch_bounds__(256, 4) void gemm_vt_dp(
    const _Float16* __restrict__ Wt,   // wvT [1024][1024]
    const _Float16* __restrict__ Xh,   // x_hi [4096][1024]
    _Float16* __restrict__ VT) {       // [1024][4096]
    __shared__ _Float16 As[3][128][32];   // 24 KB
    __shared__ _Float16 Bs[3][64][32];    // 12 KB

    const int tid  = threadIdx.x;
    const int lane = tid & 63;
    const int wid  = tid >> 6;            // 0..3
    const int wm   = (wid >> 1) * 64;     // 0,64
    const int wn   = (wid & 1) * 32;      // 0,32

    const int rowA0 = blockIdx.y * 128;
    const int colB0 = blockIdx.x * 64;

    const int ar  = tid >> 2;             // 0..63
    const int ag  = tid & 3;
    const int ags = ag ^ ((ar >> 1) & 3);
    const char* aSrc0 = (const char*)(Wt + (size_t)(rowA0 + ar) * DMODEL) + ags * 16;
    const char* aSrc1 = (const char*)(Wt + (size_t)(rowA0 + ar + 64) * DMODEL) + ags * 16;
    const char* bSrc0 = (const char*)(Xh + (size_t)(colB0 + ar) * DMODEL) + ags * 16;

#define STAGE_V(tt)                                                                 \
    do {                                                                            \
        const int _s = (tt) % 3;                                                    \
        const size_t _ko = (size_t)(tt) * 64;                                       \
        __builtin_amdgcn_global_load_lds(                                           \
            (const __attribute__((address_space(1))) void*)(aSrc0 + _ko),           \
            (__attribute__((address_space(3))) void*)&As[_s][ar][ag * 8], 16, 0, 0);\
        __builtin_amdgcn_global_load_lds(                                           \
            (const __attribute__((address_space(1))) void*)(aSrc1 + _ko),           \
            (__attribute__((address_space(3))) void*)&As[_s][ar + 64][ag * 8], 16, 0, 0);\
        __builtin_amdgcn_global_load_lds(                                           \
            (const __attribute__((address_space(1))) void*)(bSrc0 + _ko),           \
            (__attribute__((address_space(3))) void*)&Bs[_s][ar][ag * 8], 16, 0, 0);\
    } while (0)

    const int fm = lane & 15;
    const int fq = lane >> 4;
    const int ck = (fq ^ ((fm >> 1) & 3)) * 8;

    floatx4 acc[4][2] = {};

    auto tile_body = [&](int t, bool do_stage) {
        const int s = t % 3;
        half8 av[4], bv[2];
#pragma unroll
        for (int i = 0; i < 4; ++i) av[i] = *(const half8*)&As[s][wm + i * 16 + fm][ck];
#pragma unroll
        for (int j = 0; j < 2; ++j) bv[j] = *(const half8*)&Bs[s][wn + j * 16 + fm][ck];
        if (do_stage) STAGE_V(t + 2);
        asm volatile("" ::: "memory");
        __builtin_amdgcn_s_barrier();
        asm volatile("" ::: "memory");
        __builtin_amdgcn_s_setprio(1);
#pragma unroll
        for (int i = 0; i < 4; ++i)
#pragma unroll
            for (int j = 0; j < 2; ++j)
                acc[i][j] = __builtin_amdgcn_mfma_f32_16x16x32_f16(av[i], bv[j], acc[i][j], 0, 0, 0);
        __builtin_amdgcn_s_setprio(0);
    };

    STAGE_V(0);
    STAGE_V(1);
    asm volatile("s_waitcnt vmcnt(3)" ::: "memory");
    __builtin_amdgcn_s_barrier();
    asm volatile("" ::: "memory");

#pragma unroll 1
    for (int t = 0; t < 30; ++t) {
        tile_body(t, true);
        asm volatile("s_waitcnt vmcnt(3)" ::: "memory");
        __builtin_amdgcn_s_barrier();
        asm volatile("" ::: "memory");
    }
    tile_body(30, false);
    asm volatile("s_waitcnt vmcnt(0)" ::: "memory");
    __builtin_amdgcn_s_barrier();
    asm volatile("" ::: "memory");
    tile_body(31, false);
#undef STAGE_V

#pragma unroll
    for (int i = 0; i < 4; ++i) {
        const int growb = rowA0 + wm + i * 16 + fq * 4;
#pragma unroll
        for (int j = 0; j < 2; ++j) {
            const int gcol = colB0 + wn + j * 16 + fm;
#pragma unroll
            for (int r = 0; r < 4; ++r)
                VT[(size_t)(growb + r) * SEQ + gcol] = (_Float16)acc[i][j][r];
        }
    }
}

// ---------------------------------------------------------------------------
// PV GEMM, merged single phase (R13 exact), softmax-finalize scale folded
// into A-fragments: out = sum_t c[row][t] * (P_t @ V_t). Tile 128x128,
// BK=64, 8 waves, 4-slot ring (128KB) + cT 16KB, 4 vmem/tile, gate vmcnt(8).
// ---------------------------------------------------------------------------
__global__ __launch_bounds__(512, 1) void gemm_pv_dp(
    const _Float16* __restrict__ P,      // [4096][4096] (unscaled exp)
    const _Float16* __restrict__ VT,     // [1024][4096]
    const _Float16* __restrict__ CarrT,  // [64][4096]
    float* __restrict__ out) {           // [4096][1024]
    __shared__ _Float16 As[4][128][64];   // 64 KB
    __shared__ _Float16 Bs[4][128][64];   // 64 KB
    __shared__ _Float16 cT[64][128];      // 16 KB

    const int tid  = threadIdx.x;
    const int lane = tid & 63;
    const int wid  = tid >> 6;
    const int wm   = (wid >> 2) * 64;     // 0,64
    const int wn   = (wid & 3) * 32;      // 0,32,64,96

    const int rowA0 = blockIdx.y * 128;
    const int colB0 = blockIdx.x * 128;

    {
        int g = tid;
#pragma unroll
        for (int it = 0; it < 2; ++it, g += 512) {
            const int t  = g >> 4;
            const int r8 = (g & 15) * 8;
            *(half8*)&cT[t][r8] =
                *(const half8*)(CarrT + (size_t)t * SEQ + rowA0 + r8);
        }
    }
    __syncthreads();

    const int prow = tid >> 3;            // 0..63
    const int pgr  = tid & 7;
    const int ags  = pgr ^ (prow & 7);
    const char* aSrc0 = (const char*)(P  + (size_t)(rowA0 + prow) * SEQ) + ags * 16;
    const char* aSrc1 = (const char*)(P  + (size_t)(rowA0 + prow + 64) * SEQ) + ags * 16;
    const char* bSrc0 = (const char*)(VT + (size_t)(colB0 + prow) * SEQ) + ags * 16;
    const char* bSrc1 = (const char*)(VT + (size_t)(colB0 + prow + 64) * SEQ) + ags * 16;

#define STAGE_PA(tt)                                                                \
    do {                                                                            \
        const int _s = (tt) & 3;                                                    \
        const size_t _ko = (size_t)(tt) * 128;                                      \
        __builtin_amdgcn_global_load_lds(                                           \
            (const __attribute__((address_space(1))) void*)(aSrc0 + _ko),           \
            (__attribute__((address_space(3))) void*)&As[_s][prow][pgr * 8], 16, 0, 0);\
        __builtin_amdgcn_global_load_lds(                                           \
            (const __attribute__((address_space(1))) void*)(aSrc1 + _ko),           \
            (__attribute__((address_space(3))) void*)&As[_s][prow + 64][pgr * 8], 16, 0, 0);\
    } while (0)

#define STAGE_PB(tt)                                                                \
    do {                                                                            \
        const int _s = (tt) & 3;                                                    \
        const size_t _ko = (size_t)(tt) * 128;                                      \
        __builtin_amdgcn_global_load_lds(                                           \
            (const __attribute__((address_space(1))) void*)(bSrc0 + _ko),           \
            (__attribute__((address_space(3))) void*)&Bs[_s][prow][pgr * 8], 16, 0, 0);\
        __builtin_amdgcn_global_load_lds(                                           \
            (const __attribute__((address_space(1))) void*)(bSrc1 + _ko),           \
            (__attribute__((address_space(3))) void*)&Bs[_s][prow + 64][pgr * 8], 16, 0, 0);\
    } while (0)

    const int fm = lane & 15;
    const int fq = lane >> 4;
    const int ck0 = ((fq    ) ^ (fm & 7)) * 8;   // k-slice 0 (k0..k0+31)
    const int ck1 = ((fq + 4) ^ (fm & 7)) * 8;   // k-slice 1 (k0+32..k0+63)

    floatx4 acc[4][2] = {};

    auto tile_body = [&](int t, bool do_stage) {
        const int s = t & 3;
        half8 av[4], av2[4], bv[2], bv2[2];
        _Float16 cs[4];
#pragma unroll
        for (int i = 0; i < 4; ++i) {
            av[i]  = *(const half8*)&As[s][wm + i * 16 + fm][ck0];
            av2[i] = *(const half8*)&As[s][wm + i * 16 + fm][ck1];
            cs[i]  = cT[t][wm + i * 16 + fm];
        }
#pragma unroll
        for (int j = 0; j < 2; ++j) {
            bv[j]  = *(const half8*)&Bs[s][wn + j * 16 + fm][ck0];
            bv2[j] = *(const half8*)&Bs[s][wn + j * 16 + fm][ck1];
        }
#pragma unroll
        for (int i = 0; i < 4; ++i)
#pragma unroll
            for (int e = 0; e < 8; ++e) {
                av[i][e]  *= cs[i];
                av2[i][e] *= cs[i];
            }
        if (do_stage) { STAGE_PA(t + 3); STAGE_PB(t + 3); }
        asm volatile("" ::: "memory");
        __builtin_amdgcn_s_barrier();
        asm volatile("" ::: "memory");
        __builtin_amdgcn_s_setprio(1);
#pragma unroll
        for (int i = 0; i < 4; ++i)
#pragma unroll
            for (int j = 0; j < 2; ++j)
                acc[i][j] = __builtin_amdgcn_mfma_f32_16x16x32_f16(av[i], bv[j], acc[i][j], 0, 0, 0);
#pragma unroll
        for (int i = 0; i < 4; ++i)
#pragma unroll
            for (int j = 0; j < 2; ++j)
                acc[i][j] = __builtin_amdgcn_mfma_f32_16x16x32_f16(av2[i], bv2[j], acc[i][j], 0, 0, 0);
        __builtin_amdgcn_s_setprio(0);
    };

    STAGE_PA(0); STAGE_PB(0);
    STAGE_PA(1); STAGE_PB(1);
    STAGE_PA(2); STAGE_PB(2);
    asm volatile("s_waitcnt vmcnt(8)" ::: "memory");
    __builtin_amdgcn_s_barrier();
    asm volatile("" ::: "memory");

#pragma unroll 1
    for (int t = 0; t < 61; ++t) {
        tile_body(t, true);
        asm volatile("s_waitcnt vmcnt(8)" ::: "memory");
        __builtin_amdgcn_s_barrier();
        asm volatile("" ::: "memory");
    }
    tile_body(61, false);
    asm volatile("s_waitcnt vmcnt(4)" ::: "memory");
    __builtin_amdgcn_s_barrier();
    asm volatile("" ::: "memory");
    tile_body(62, false);
    asm volatile("s_waitcnt vmcnt(0)" ::: "memory");
    __builtin_amdgcn_s_barrier();
    asm volatile("" ::: "memory");
    tile_body(63, false);
#undef STAGE_PA
#undef STAGE_PB

#pragma unroll
    for (int i = 0; i < 4; ++i) {
        const int growb = rowA0 + wm + i * 16 + fq * 4;
#pragma unroll
        for (int j = 0; j < 2; ++j) {
            const int gcol = colB0 + wn + j * 16 + fm;
#pragma unroll
            for (int r = 0; r < 4; ++r)
                out[(size_t)(growb + r) * DMODEL + gcol] = acc[i][j][r];
        }
    }
}

// ---------------------------------------------------------------------------
// Workspace layout (104 MB used):
//  [0,32M)    P fp16 [4096][4096] (region reused: x_hi [0,8M), x_lo [8,16M),
//             wqkT_hi [16,20M), wqkT_lo [20,24M), wvT [24,26M) all dead
//             before the score kernel writes P)
//  [32,33M)   Marr fp32 [4096][64]   [33,34M) Larr fp32 [4096][64]
//  [34,34.5M) CarrT fp16 [64][4096]
//  [64,72M)   Qh fp16 [4096][1024]
//  [72,80M)   Kh fp16 [4096][1024]
//  [96,104M)  VT fp16 [1024][4096]
// ---------------------------------------------------------------------------
extern "C" void kernel_launch(void* const* d_in, const int* in_sizes, int n_in,
                              void* d_out, int out_size, void* d_ws, size_t ws_size,
                              hipStream_t stream) {
    const float* x  = (const float*)d_in[0];
    const float* wq = (const float*)d_in[1];
    const float* wk = (const float*)d_in[2];
    const float* wv = (const float*)d_in[3];
    float* out = (float*)d_out;

    char* base = (char*)d_ws;
    const size_t MB = 1u << 20;
    _Float16* P       = (_Float16*)base;               // [4096][4096]
    _Float16* x_hi    = (_Float16*)(base + 0 * MB);
    _Float16* x_lo    = (_Float16*)(base + 8 * MB);
    _Float16* wqkT_hi = (_Float16*)(base + 16 * MB);   // [2048][1024]
    _Float16* wqkT_lo = (_Float16*)(base + 20 * MB);
    _Float16* wvT     = (_Float16*)(base + 24 * MB);   // [1024][1024]
    float*    Marr    = (float*)(base + 32 * MB);
    float*    Larr    = (float*)(base + 33 * MB);
    _Float16* CarrT   = (_Float16*)(base + 34 * MB);   // [64][4096]
    _Float16* Qh      = (_Float16*)(base + 64 * MB);   // [4096][1024]
    _Float16* Kh      = (_Float16*)(base + 72 * MB);   // [4096][1024]
    _Float16* VT      = (_Float16*)(base + 96 * MB);   // [1024][4096]

    // 1) fused prep (hi/lo splits — 3-product needs them)
    prep<<<4096, 256, 0, stream>>>(x, wq, wk, wv, x_hi, x_lo, wqkT_hi, wqkT_lo, wvT);

    // 2) QK projection, consolidated 3-product (48 MFMA/window, 32 K-tiles)
    dim3 gqk(2048 / 256, SEQ / 128);   // (8,32) — XCD = col-panel
    gemm_qkproj_dp<<<gqk, dim3(512), 0, stream>>>(x_hi, x_lo, wqkT_hi, wqkT_lo,
                                                  Qh, Kh);
    // V^T = wvT @ x_hi^T, modernized ring (3-slot, distance-2 prefetch)
    dim3 gvt(SEQ / 64, DMODEL / 128);  // (64,8) = 512 blocks, 2/CU
    gemm_vt_dp<<<gvt, 256, 0, stream>>>(wvT, x_hi, VT);

    // 3) scores + tile-softmax, tile 256x128 -> 512 blocks = 2 blocks/CU
    dim3 gs(SEQ / 128, SEQ / 256);     // (32,16)
    gemm_score_dp<<<gs, dim3(512), 0, stream>>>(Qh, Kh, P, Marr, Larr,
                                                1.0f / 32.0f);

    // 4) finalize coefficients only (no P traffic), coalesced writes
    compute_c<<<SEQ / 64, 256, 0, stream>>>(Marr, Larr, CarrT);

    // 5) out = sum_t c_t * (P_t @ V_t), merged-phase ring
    dim3 gpv(DMODEL / 128, SEQ / 128); // (8,32) — XCD = col-panel
    gemm_pv_dp<<<gpv, dim3(512), 0, stream>>>(P, VT, CarrT, out);
}

// Round 16
// 246.510 us; speedup vs baseline: 1.0442x; 1.0368x over previous
//
#include <hip/hip_runtime.h>
#include <hip/hip_fp16.h>
#include <math.h>

#define SEQ    4096
#define DMODEL 1024

typedef _Float16 half8   __attribute__((ext_vector_type(8)));
typedef _Float16 half4v  __attribute__((ext_vector_type(4)));
typedef float    floatx4 __attribute__((ext_vector_type(4)));

__device__ inline void split_val(float v, _Float16& h, _Float16& l) {
    _Float16 hh = (_Float16)v;
    h = hh;
    l = (_Float16)(v - (float)hh);
}

// ---------------------------------------------------------------------------
// Fused prep (R13): blocks 0..3071 transpose wq/wk/wv (32x32 tiles) into
// hi/lo fp16; blocks 3072..4095 split x into hi/lo fp16.
// ---------------------------------------------------------------------------
__global__ __launch_bounds__(256) void prep(const float* __restrict__ x,
                                            const float* __restrict__ wq,
                                            const float* __restrict__ wk,
                                            const float* __restrict__ wv,
                                            _Float16* __restrict__ x_hi,
                                            _Float16* __restrict__ x_lo,
                                            _Float16* __restrict__ wqkT_hi,
                                            _Float16* __restrict__ wqkT_lo,
                                            _Float16* __restrict__ wvT) {
    __shared__ float tile[32][33];
    const int b = blockIdx.x;
    if (b < 3072) {
        const int which = b >> 10;           // 0=wq 1=wk 2=wv
        const int bb = b & 1023;
        const int c0 = (bb & 31) * 32;
        const int r0 = (bb >> 5) * 32;
        const float* w = (which == 0) ? wq : (which == 1) ? wk : wv;
        const int tx = threadIdx.x & 31, ty = threadIdx.x >> 5;
#pragma unroll
        for (int j = 0; j < 4; ++j)
            tile[ty * 4 + j][tx] = w[(size_t)(r0 + ty * 4 + j) * DMODEL + c0 + tx];
        __syncthreads();
        if (which < 2) {
            _Float16* th = wqkT_hi + (size_t)which * DMODEL * DMODEL;
            _Float16* tl = wqkT_lo + (size_t)which * DMODEL * DMODEL;
#pragma unroll
            for (int j = 0; j < 4; ++j) {
                float v = tile[tx][ty * 4 + j];
                size_t idx = (size_t)(c0 + ty * 4 + j) * DMODEL + r0 + tx;
                _Float16 h, l;
                split_val(v, h, l);
                th[idx] = h;
                tl[idx] = l;
            }
        } else {
#pragma unroll
            for (int j = 0; j < 4; ++j)
                wvT[(size_t)(c0 + ty * 4 + j) * DMODEL + r0 + tx] =
                    (_Float16)tile[tx][ty * 4 + j];
        }
    } else {
        const int t0 = (b - 3072) * 256 + threadIdx.x;
#pragma unroll
        for (int rep = 0; rep < 4; ++rep) {
            const size_t i = (size_t)t0 + (size_t)rep * 262144;
            floatx4 v = *(const floatx4*)(x + 4 * i);
            half4v h, l;
#pragma unroll
            for (int j = 0; j < 4; ++j) {
                _Float16 hh = (_Float16)v[j];
                _Float16 ll = (_Float16)(v[j] - (float)hh);
                h[j] = hh;
                l[j] = ll;
            }
            *(half4v*)(x_hi + 4 * i) = h;
            *(half4v*)(x_lo + 4 * i) = l;
        }
    }
}

// ---------------------------------------------------------------------------
// QK projection, consolidated 3-product (R13 exact — measured 56us, 922 TF
// = the ~37% structural plateau): per K-tile stage {A_hi, A_lo, B_hi, B_lo}
// (6 loads), 48 MFMA per window. Tile 128x256, BK=32, 32 K-tiles, 3-slot
// ring (144KB), gate vmcnt(6).
// ---------------------------------------------------------------------------
__global__ __launch_bounds__(512, 1) void gemm_qkproj_dp(
    const _Float16* __restrict__ Ahi, const _Float16* __restrict__ Alo,   // x_hi/x_lo [4096][1024]
    const _Float16* __restrict__ Bhi, const _Float16* __restrict__ Blo,   // wqkT_hi/lo [2048][1024]
    _Float16* __restrict__ Qh, _Float16* __restrict__ Kh) {
    __shared__ _Float16 Ah[3][128][32];   // 24 KB
    __shared__ _Float16 Al[3][128][32];   // 24 KB
    __shared__ _Float16 Bh[3][256][32];   // 48 KB
    __shared__ _Float16 Bl[3][256][32];   // 48 KB

    const int tid  = threadIdx.x;
    const int lane = tid & 63;
    const int wid  = tid >> 6;
    const int wm   = (wid >> 2) * 64;     // 0,64
    const int wn   = (wid & 3) * 64;      // 0,64,128,192

    const int rowA0 = blockIdx.y * 128;
    const int colB0 = blockIdx.x * 256;

    const int ar  = tid >> 2;             // 0..127
    const int ag  = tid & 3;
    const int ags = ag ^ ((ar >> 1) & 3);
    const char* aHiS = (const char*)(Ahi + (size_t)(rowA0 + ar) * DMODEL) + ags * 16;
    const char* aLoS = (const char*)(Alo + (size_t)(rowA0 + ar) * DMODEL) + ags * 16;
    const char* bHi0 = (const char*)(Bhi + (size_t)(colB0 + ar) * DMODEL) + ags * 16;
    const char* bHi1 = (const char*)(Bhi + (size_t)(colB0 + ar + 128) * DMODEL) + ags * 16;
    const char* bLo0 = (const char*)(Blo + (size_t)(colB0 + ar) * DMODEL) + ags * 16;
    const char* bLo1 = (const char*)(Blo + (size_t)(colB0 + ar + 128) * DMODEL) + ags * 16;

#define STAGE_Q(tt)                                                                  \
    do {                                                                             \
        const int _s = (tt) % 3;                                                     \
        const size_t _ko = (size_t)(tt) * 64;                                        \
        __builtin_amdgcn_global_load_lds(                                            \
            (const __attribute__((address_space(1))) void*)(aHiS + _ko),             \
            (__attribute__((address_space(3))) void*)&Ah[_s][ar][ag * 8], 16, 0, 0); \
        __builtin_amdgcn_global_load_lds(                                            \
            (const __attribute__((address_space(1))) void*)(aLoS + _ko),             \
            (__attribute__((address_space(3))) void*)&Al[_s][ar][ag * 8], 16, 0, 0); \
        __builtin_amdgcn_global_load_lds(                                            \
            (const __attribute__((address_space(1))) void*)(bHi0 + _ko),             \
            (__attribute__((address_space(3))) void*)&Bh[_s][ar][ag * 8], 16, 0, 0); \
        __builtin_amdgcn_global_load_lds(                                            \
            (const __attribute__((address_space(1))) void*)(bHi1 + _ko),             \
            (__attribute__((address_space(3))) void*)&Bh[_s][ar + 128][ag * 8], 16, 0, 0);\
        __builtin_amdgcn_global_load_lds(                                            \
            (const __attribute__((address_space(1))) void*)(bLo0 + _ko),             \
            (__attribute__((address_space(3))) void*)&Bl[_s][ar][ag * 8], 16, 0, 0); \
        __builtin_amdgcn_global_load_lds(                                            \
            (const __attribute__((address_space(1))) void*)(bLo1 + _ko),             \
            (__attribute__((address_space(3))) void*)&Bl[_s][ar + 128][ag * 8], 16, 0, 0);\
    } while (0)

    const int fm = lane & 15;
    const int fq = lane >> 4;
    const int ck = (fq ^ ((fm >> 1) & 3)) * 8;

    floatx4 acc[4][4] = {};

    auto tile_body = [&](int t, bool do_stage) {
        const int s = t % 3;
        half8 avh[4], avl[4], bvh[4], bvl[4];
#pragma unroll
        for (int i = 0; i < 4; ++i) {
            avh[i] = *(const half8*)&Ah[s][wm + i * 16 + fm][ck];
            avl[i] = *(const half8*)&Al[s][wm + i * 16 + fm][ck];
        }
#pragma unroll
        for (int j = 0; j < 4; ++j) {
            bvh[j] = *(const half8*)&Bh[s][wn + j * 16 + fm][ck];
            bvl[j] = *(const half8*)&Bl[s][wn + j * 16 + fm][ck];
        }
        if (do_stage) STAGE_Q(t + 2);
        asm volatile("" ::: "memory");
        __builtin_amdgcn_s_barrier();
        asm volatile("" ::: "memory");
        __builtin_amdgcn_s_setprio(1);
#pragma unroll
        for (int i = 0; i < 4; ++i)
#pragma unroll
            for (int j = 0; j < 4; ++j)
                acc[i][j] = __builtin_amdgcn_mfma_f32_16x16x32_f16(avh[i], bvh[j], acc[i][j], 0, 0, 0);
#pragma unroll
        for (int i = 0; i < 4; ++i)
#pragma unroll
            for (int j = 0; j < 4; ++j)
                acc[i][j] = __builtin_amdgcn_mfma_f32_16x16x32_f16(avh[i], bvl[j], acc[i][j], 0, 0, 0);
#pragma unroll
        for (int i = 0; i < 4; ++i)
#pragma unroll
            for (int j = 0; j < 4; ++j)
                acc[i][j] = __builtin_amdgcn_mfma_f32_16x16x32_f16(avl[i], bvh[j], acc[i][j], 0, 0, 0);
        __builtin_amdgcn_s_setprio(0);
    };

    STAGE_Q(0);
    STAGE_Q(1);
    asm volatile("s_waitcnt vmcnt(6)" ::: "memory");
    __builtin_amdgcn_s_barrier();
    asm volatile("" ::: "memory");

#pragma unroll 1
    for (int t = 0; t < 30; ++t) {
        tile_body(t, true);
        asm volatile("s_waitcnt vmcnt(6)" ::: "memory");
        __builtin_amdgcn_s_barrier();
        asm volatile("" ::: "memory");
    }
    tile_body(30, false);
    asm volatile("s_waitcnt vmcnt(0)" ::: "memory");
    __builtin_amdgcn_s_barrier();
    asm volatile("" ::: "memory");
    tile_body(31, false);
#undef STAGE_Q

    _Float16* dst = Qh;
    int cbase = colB0;
    if (colB0 >= 1024) { dst = Kh; cbase = colB0 - 1024; }

#pragma unroll
    for (int i = 0; i < 4; ++i) {
        const int growb = rowA0 + wm + i * 16 + fq * 4;
#pragma unroll
        for (int j = 0; j < 4; ++j) {
            const int gcol = wn + j * 16 + fm;
#pragma unroll
            for (int r = 0; r < 4; ++r)
                dst[(size_t)(growb + r) * DMODEL + cbase + gcol] =
                    (_Float16)acc[i][j][r];
        }
    }
}

// ---------------------------------------------------------------------------
// Score GEMM (R14 exact): tile 256x128, grid 512 blocks = 2 blocks/CU,
// 8 waves (4Mx2N), per-wave 64x64. 3-slot ring (72KB), gate vmcnt(3).
// S = Qh @ Kh^T, K=1024. Tile-softmax epilogue (64-col spans).
// ---------------------------------------------------------------------------
__global__ __launch_bounds__(512, 4) void gemm_score_dp(
    const _Float16* __restrict__ Qh,   // [4096][1024]
    const _Float16* __restrict__ Kh,   // [4096][1024]
    _Float16* __restrict__ Ph, float* __restrict__ Marr, float* __restrict__ Larr,
    float scale) {
    __shared__ _Float16 As[3][256][32];   // 48 KB
    __shared__ _Float16 Bs[3][128][32];   // 24 KB

    const int tid  = threadIdx.x;
    const int lane = tid & 63;
    const int wid  = tid >> 6;
    const int wm   = (wid >> 1) * 64;     // 0,64,128,192
    const int wn   = (wid & 1) * 64;      // 0,64

    // XCD-aware bijective swizzle: nwg = 512 (grid 32 x 16), 512 = 8*64.
    const int lin = blockIdx.y * 32 + blockIdx.x;
    const int swz = (lin & 7) * 64 + (lin >> 3);
    const int rowA0 = (swz >> 5) * 256;
    const int colB0 = (swz & 31) * 128;

    const int pr  = tid >> 2;
    const int pg  = tid & 3;
    const int pgs = pg ^ ((pr >> 1) & 3);
    const char* aSrc0 = (const char*)(Qh + (size_t)(rowA0 + pr) * DMODEL) + pgs * 16;
    const char* aSrc1 = (const char*)(Qh + (size_t)(rowA0 + pr + 128) * DMODEL) + pgs * 16;
    const char* bSrc0 = (const char*)(Kh + (size_t)(colB0 + pr) * DMODEL) + pgs * 16;

#define STAGE_S(t)                                                                  \
    do {                                                                            \
        const int _s = (t) % 3;                                                     \
        const size_t _ko = (size_t)(t) * 64;                                        \
        __builtin_amdgcn_global_load_lds(                                           \
            (const __attribute__((address_space(1))) void*)(aSrc0 + _ko),           \
            (__attribute__((address_space(3))) void*)&As[_s][pr][pg * 8], 16, 0, 0);\
        __builtin_amdgcn_global_load_lds(                                           \
            (const __attribute__((address_space(1))) void*)(aSrc1 + _ko),           \
            (__attribute__((address_space(3))) void*)&As[_s][pr + 128][pg * 8], 16, 0, 0);\
        __builtin_amdgcn_global_load_lds(                                           \
            (const __attribute__((address_space(1))) void*)(bSrc0 + _ko),           \
            (__attribute__((address_space(3))) void*)&Bs[_s][pr][pg * 8], 16, 0, 0);\
    } while (0)

    const int fm = lane & 15;
    const int fq = lane >> 4;
    const int ck = (fq ^ ((fm >> 1) & 3)) * 8;

    floatx4 acc[4][4] = {};

    auto tile_body = [&](int t, bool do_stage) {
        const int s = t % 3;
        half8 av[4], bv[4];
#pragma unroll
        for (int i = 0; i < 4; ++i) av[i] = *(const half8*)&As[s][wm + i * 16 + fm][ck];
#pragma unroll
        for (int j = 0; j < 4; ++j) bv[j] = *(const half8*)&Bs[s][wn + j * 16 + fm][ck];
        if (do_stage) STAGE_S(t + 2);
        asm volatile("" ::: "memory");
        __builtin_amdgcn_s_barrier();
        asm volatile("" ::: "memory");
        __builtin_amdgcn_s_setprio(1);
#pragma unroll
        for (int i = 0; i < 4; ++i)
#pragma unroll
            for (int j = 0; j < 4; ++j)
                acc[i][j] = __builtin_amdgcn_mfma_f32_16x16x32_f16(av[i], bv[j], acc[i][j], 0, 0, 0);
        __builtin_amdgcn_s_setprio(0);
    };

    STAGE_S(0);
    STAGE_S(1);
    asm volatile("s_waitcnt vmcnt(3)" ::: "memory");
    __builtin_amdgcn_s_barrier();
    asm volatile("" ::: "memory");

#pragma unroll 1
    for (int t = 0; t < 30; ++t) {
        tile_body(t, true);
        asm volatile("s_waitcnt vmcnt(3)" ::: "memory");
        __builtin_amdgcn_s_barrier();
        asm volatile("" ::: "memory");
    }
    tile_body(30, false);
    asm volatile("s_waitcnt vmcnt(0)" ::: "memory");
    __builtin_amdgcn_s_barrier();
    asm volatile("" ::: "memory");
    tile_body(31, false);
#undef STAGE_S

    const int tprime = (colB0 + wn) >> 6;
#pragma unroll
    for (int i = 0; i < 4; ++i) {
#pragma unroll
        for (int r = 0; r < 4; ++r) {
            const int grow = rowA0 + wm + i * 16 + fq * 4 + r;
            float s0 = acc[i][0][r] * scale;
            float s1 = acc[i][1][r] * scale;
            float s2 = acc[i][2][r] * scale;
            float s3 = acc[i][3][r] * scale;
            float mx = fmaxf(fmaxf(s0, s1), fmaxf(s2, s3));
            mx = fmaxf(mx, __shfl_xor(mx, 1));
            mx = fmaxf(mx, __shfl_xor(mx, 2));
            mx = fmaxf(mx, __shfl_xor(mx, 4));
            mx = fmaxf(mx, __shfl_xor(mx, 8));
            float p0 = __expf(s0 - mx);
            float p1 = __expf(s1 - mx);
            float p2 = __expf(s2 - mx);
            float p3 = __expf(s3 - mx);
            float sum = p0 + p1 + p2 + p3;
            sum += __shfl_xor(sum, 1);
            sum += __shfl_xor(sum, 2);
            sum += __shfl_xor(sum, 4);
            sum += __shfl_xor(sum, 8);
            _Float16* prow = Ph + (size_t)grow * SEQ + colB0 + wn + fm;
            prow[0]  = (_Float16)p0;
            prow[16] = (_Float16)p1;
            prow[32] = (_Float16)p2;
            prow[48] = (_Float16)p3;
            if (fm == 0) {
                Marr[(size_t)grow * 64 + tprime] = mx;
                Larr[(size_t)grow * 64 + tprime] = sum;
            }
        }
    }
}

// ---------------------------------------------------------------------------
// compute_c, coalesced: 64 rows per block (grid 64, 256 threads = 4 waves).
// ---------------------------------------------------------------------------
__global__ __launch_bounds__(256) void compute_c(const float* __restrict__ Marr,
                                                 const float* __restrict__ Larr,
                                                 _Float16* __restrict__ CarrT) {
    __shared__ float c_s[64][65];
    const int row0 = blockIdx.x * 64;
    const int wv = threadIdx.x >> 6;
    const int ln = threadIdx.x & 63;

#pragma unroll
    for (int k = 0; k < 16; ++k) {
        const int r = wv * 16 + k;
        float mt = Marr[(size_t)(row0 + r) * 64 + ln];
        float lt = Larr[(size_t)(row0 + r) * 64 + ln];
        float m = mt;
#pragma unroll
        for (int off = 32; off > 0; off >>= 1) m = fmaxf(m, __shfl_xor(m, off));
        float e = __expf(mt - m);
        float L = lt * e;
#pragma unroll
        for (int off = 32; off > 0; off >>= 1) L += __shfl_xor(L, off);
        c_s[r][ln] = e / L;
    }
    __syncthreads();

#pragma unroll
    for (int k = 0; k < 16; ++k) {
        const int t = wv * 16 + k;
        CarrT[(size_t)t * SEQ + row0 + ln] = (_Float16)c_s[ln][t];
    }
}

// ---------------------------------------------------------------------------
// V^T projection, modernized ring (R15): tile 128x64, BK=32, 256 threads,
// 3-slot ring (36KB), gate vmcnt(3), distance-2 prefetch.
// ---------------------------------------------------------------------------
__global__ __launch_bounds__(256, 4) void gemm_vt_dp(
    const _Float16* __restrict__ Wt,   // wvT [1024][1024]
    const _Float16* __restrict__ Xh,   // x_hi [4096][1024]
    _Float16* __restrict__ VT) {       // [1024][4096]
    __shared__ _Float16 As[3][128][32];   // 24 KB
    __shared__ _Float16 Bs[3][64][32];    // 12 KB

    const int tid  = threadIdx.x;
    const int lane = tid & 63;
    const int wid  = tid >> 6;            // 0..3
    const int wm   = (wid >> 1) * 64;     // 0,64
    const int wn   = (wid & 1) * 32;      // 0,32

    const int rowA0 = blockIdx.y * 128;
    const int colB0 = blockIdx.x * 64;

    const int ar  = tid >> 2;             // 0..63
    const int ag  = tid & 3;
    const int ags = ag ^ ((ar >> 1) & 3);
    const char* aSrc0 = (const char*)(Wt + (size_t)(rowA0 + ar) * DMODEL) + ags * 16;
    const char* aSrc1 = (const char*)(Wt + (size_t)(rowA0 + ar + 64) * DMODEL) + ags * 16;
    const char* bSrc0 = (const char*)(Xh + (size_t)(colB0 + ar) * DMODEL) + ags * 16;

#define STAGE_V(tt)                                                                 \
    do {                                                                            \
        const int _s = (tt) % 3;                                                    \
        const size_t _ko = (size_t)(tt) * 64;                                       \
        __builtin_amdgcn_global_load_lds(                                           \
            (const __attribute__((address_space(1))) void*)(aSrc0 + _ko),           \
            (__attribute__((address_space(3))) void*)&As[_s][ar][ag * 8], 16, 0, 0);\
        __builtin_amdgcn_global_load_lds(                                           \
            (const __attribute__((address_space(1))) void*)(aSrc1 + _ko),           \
            (__attribute__((address_space(3))) void*)&As[_s][ar + 64][ag * 8], 16, 0, 0);\
        __builtin_amdgcn_global_load_lds(                                           \
            (const __attribute__((address_space(1))) void*)(bSrc0 + _ko),           \
            (__attribute__((address_space(3))) void*)&Bs[_s][ar][ag * 8], 16, 0, 0);\
    } while (0)

    const int fm = lane & 15;
    const int fq = lane >> 4;
    const int ck = (fq ^ ((fm >> 1) & 3)) * 8;

    floatx4 acc[4][2] = {};

    auto tile_body = [&](int t, bool do_stage) {
        const int s = t % 3;
        half8 av[4], bv[2];
#pragma unroll
        for (int i = 0; i < 4; ++i) av[i] = *(const half8*)&As[s][wm + i * 16 + fm][ck];
#pragma unroll
        for (int j = 0; j < 2; ++j) bv[j] = *(const half8*)&Bs[s][wn + j * 16 + fm][ck];
        if (do_stage) STAGE_V(t + 2);
        asm volatile("" ::: "memory");
        __builtin_amdgcn_s_barrier();
        asm volatile("" ::: "memory");
        __builtin_amdgcn_s_setprio(1);
#pragma unroll
        for (int i = 0; i < 4; ++i)
#pragma unroll
            for (int j = 0; j < 2; ++j)
                acc[i][j] = __builtin_amdgcn_mfma_f32_16x16x32_f16(av[i], bv[j], acc[i][j], 0, 0, 0);
        __builtin_amdgcn_s_setprio(0);
    };

    STAGE_V(0);
    STAGE_V(1);
    asm volatile("s_waitcnt vmcnt(3)" ::: "memory");
    __builtin_amdgcn_s_barrier();
    asm volatile("" ::: "memory");

#pragma unroll 1
    for (int t = 0; t < 30; ++t) {
        tile_body(t, true);
        asm volatile("s_waitcnt vmcnt(3)" ::: "memory");
        __builtin_amdgcn_s_barrier();
        asm volatile("" ::: "memory");
    }
    tile_body(30, false);
    asm volatile("s_waitcnt vmcnt(0)" ::: "memory");
    __builtin_amdgcn_s_barrier();
    asm volatile("" ::: "memory");
    tile_body(31, false);
#undef STAGE_V

#pragma unroll
    for (int i = 0; i < 4; ++i) {
        const int growb = rowA0 + wm + i * 16 + fq * 4;
#pragma unroll
        for (int j = 0; j < 2; ++j) {
            const int gcol = colB0 + wn + j * 16 + fm;
#pragma unroll
            for (int r = 0; r < 4; ++r)
                VT[(size_t)(growb + r) * SEQ + gcol] = (_Float16)acc[i][j][r];
        }
    }
}

// ---------------------------------------------------------------------------
// PV GEMM (R16): 2-SLOT ring, 80KB LDS -> 2 blocks/CU (was 144KB = 1
// block/CU, the exact disease R14's counters diagnosed in the score:
// un-hidden fences, no co-resident work; fixing it there cut the score
// >=16us). m97-proven shape: 2-slot + per-tile full drain + multi-block
// overlap. Ledger: stage(t+1) in window t writes slot (t+1)&1 == (t-1)&1,
// whose reads drained (compiler lgkm before t-1's MFMAs) ahead of t-1's
// end fence; gate vmcnt(0) per tile (drain hidden by co-resident block).
// out = sum_t c[row][t] * (P_t @ V_t), tile 128x128, BK=64, 8 waves,
// softmax-finalize scale folded into A-fragments.
// ---------------------------------------------------------------------------
__global__ __launch_bounds__(512, 4) void gemm_pv_dp(
    const _Float16* __restrict__ P,      // [4096][4096] (unscaled exp)
    const _Float16* __restrict__ VT,     // [1024][4096]
    const _Float16* __restrict__ CarrT,  // [64][4096]
    float* __restrict__ out) {           // [4096][1024]
    __shared__ _Float16 As[2][128][64];   // 32 KB
    __shared__ _Float16 Bs[2][128][64];   // 32 KB
    __shared__ _Float16 cT[64][128];      // 16 KB

    const int tid  = threadIdx.x;
    const int lane = tid & 63;
    const int wid  = tid >> 6;
    const int wm   = (wid >> 2) * 64;     // 0,64
    const int wn   = (wid & 3) * 32;      // 0,32,64,96

    const int rowA0 = blockIdx.y * 128;
    const int colB0 = blockIdx.x * 128;

    // Preload this block's c slab: cT[t][r] = CarrT[t][rowA0+r].
    {
        int g = tid;
#pragma unroll
        for (int it = 0; it < 2; ++it, g += 512) {
            const int t  = g >> 4;
            const int r8 = (g & 15) * 8;
            *(half8*)&cT[t][r8] =
                *(const half8*)(CarrT + (size_t)t * SEQ + rowA0 + r8);
        }
    }

    const int prow = tid >> 3;            // 0..63
    const int pgr  = tid & 7;
    const int ags  = pgr ^ (prow & 7);
    const char* aSrc0 = (const char*)(P  + (size_t)(rowA0 + prow) * SEQ) + ags * 16;
    const char* aSrc1 = (const char*)(P  + (size_t)(rowA0 + prow + 64) * SEQ) + ags * 16;
    const char* bSrc0 = (const char*)(VT + (size_t)(colB0 + prow) * SEQ) + ags * 16;
    const char* bSrc1 = (const char*)(VT + (size_t)(colB0 + prow + 64) * SEQ) + ags * 16;

#define STAGE_P(tt)                                                                 \
    do {                                                                            \
        const int _s = (tt) & 1;                                                    \
        const size_t _ko = (size_t)(tt) * 128;                                      \
        __builtin_amdgcn_global_load_lds(                                           \
            (const __attribute__((address_space(1))) void*)(aSrc0 + _ko),           \
            (__attribute__((address_space(3))) void*)&As[_s][prow][pgr * 8], 16, 0, 0);\
        __builtin_amdgcn_global_load_lds(                                           \
            (const __attribute__((address_space(1))) void*)(aSrc1 + _ko),           \
            (__attribute__((address_space(3))) void*)&As[_s][prow + 64][pgr * 8], 16, 0, 0);\
        __builtin_amdgcn_global_load_lds(                                           \
            (const __attribute__((address_space(1))) void*)(bSrc0 + _ko),           \
            (__attribute__((address_space(3))) void*)&Bs[_s][prow][pgr * 8], 16, 0, 0);\
        __builtin_amdgcn_global_load_lds(                                           \
            (const __attribute__((address_space(1))) void*)(bSrc1 + _ko),           \
            (__attribute__((address_space(3))) void*)&Bs[_s][prow + 64][pgr * 8], 16, 0, 0);\
    } while (0)

    const int fm = lane & 15;
    const int fq = lane >> 4;
    const int ck0 = ((fq    ) ^ (fm & 7)) * 8;   // k-slice 0 (k0..k0+31)
    const int ck1 = ((fq + 4) ^ (fm & 7)) * 8;   // k-slice 1 (k0+32..k0+63)

    floatx4 acc[4][2] = {};

    auto tile_body = [&](int t, bool do_stage) {
        const int s = t & 1;
        half8 av[4], av2[4], bv[2], bv2[2];
        _Float16 cs[4];
#pragma unroll
        for (int i = 0; i < 4; ++i) {
            av[i]  = *(const half8*)&As[s][wm + i * 16 + fm][ck0];
            av2[i] = *(const half8*)&As[s][wm + i * 16 + fm][ck1];
            cs[i]  = cT[t][wm + i * 16 + fm];
        }
#pragma unroll
        for (int j = 0; j < 2; ++j) {
            bv[j]  = *(const half8*)&Bs[s][wn + j * 16 + fm][ck0];
            bv2[j] = *(const half8*)&Bs[s][wn + j * 16 + fm][ck1];
        }
#pragma unroll
        for (int i = 0; i < 4; ++i)
#pragma unroll
            for (int e = 0; e < 8; ++e) {
                av[i][e]  *= cs[i];
                av2[i][e] *= cs[i];
            }
        if (do_stage) STAGE_P(t + 1);
        asm volatile("" ::: "memory");
        __builtin_amdgcn_s_barrier();
        asm volatile("" ::: "memory");
        __builtin_amdgcn_s_setprio(1);
#pragma unroll
        for (int i = 0; i < 4; ++i)
#pragma unroll
            for (int j = 0; j < 2; ++j)
                acc[i][j] = __builtin_amdgcn_mfma_f32_16x16x32_f16(av[i], bv[j], acc[i][j], 0, 0, 0);
#pragma unroll
        for (int i = 0; i < 4; ++i)
#pragma unroll
            for (int j = 0; j < 2; ++j)
                acc[i][j] = __builtin_amdgcn_mfma_f32_16x16x32_f16(av2[i], bv2[j], acc[i][j], 0, 0, 0);
        __builtin_amdgcn_s_setprio(0);
    };

    // Prologue: stage tile 0; full drain (also covers cT LDS writes).
    STAGE_P(0);
    asm volatile("s_waitcnt vmcnt(0) lgkmcnt(0)" ::: "memory");
    __builtin_amdgcn_s_barrier();
    asm volatile("" ::: "memory");

    // 64 K-tiles (K = 4096, BK = 64): per-tile full drain, 2-slot ring.
#pragma unroll 1
    for (int t = 0; t < 63; ++t) {
        tile_body(t, true);
        asm volatile("s_waitcnt vmcnt(0)" ::: "memory");
        __builtin_amdgcn_s_barrier();
        asm volatile("" ::: "memory");
    }
    tile_body(63, false);
#undef STAGE_P

#pragma unroll
    for (int i = 0; i < 4; ++i) {
        const int growb = rowA0 + wm + i * 16 + fq * 4;
#pragma unroll
        for (int j = 0; j < 2; ++j) {
            const int gcol = colB0 + wn + j * 16 + fm;
#pragma unroll
            for (int r = 0; r < 4; ++r)
                out[(size_t)(growb + r) * DMODEL + gcol] = acc[i][j][r];
        }
    }
}

// ---------------------------------------------------------------------------
// Workspace layout (104 MB used):
//  [0,32M)    P fp16 [4096][4096] (region reused: x_hi [0,8M), x_lo [8,16M),
//             wqkT_hi [16,20M), wqkT_lo [20,24M), wvT [24,26M) all dead
//             before the score kernel writes P)
//  [32,33M)   Marr fp32 [4096][64]   [33,34M) Larr fp32 [4096][64]
//  [34,34.5M) CarrT fp16 [64][4096]
//  [64,72M)   Qh fp16 [4096][1024]
//  [72,80M)   Kh fp16 [4096][1024]
//  [96,104M)  VT fp16 [1024][4096]
// ---------------------------------------------------------------------------
extern "C" void kernel_launch(void* const* d_in, const int* in_sizes, int n_in,
                              void* d_out, int out_size, void* d_ws, size_t ws_size,
                              hipStream_t stream) {
    const float* x  = (const float*)d_in[0];
    const float* wq = (const float*)d_in[1];
    const float* wk = (const float*)d_in[2];
    const float* wv = (const float*)d_in[3];
    float* out = (float*)d_out;

    char* base = (char*)d_ws;
    const size_t MB = 1u << 20;
    _Float16* P       = (_Float16*)base;               // [4096][4096]
    _Float16* x_hi    = (_Float16*)(base + 0 * MB);
    _Float16* x_lo    = (_Float16*)(base + 8 * MB);
    _Float16* wqkT_hi = (_Float16*)(base + 16 * MB);   // [2048][1024]
    _Float16* wqkT_lo = (_Float16*)(base + 20 * MB);
    _Float16* wvT     = (_Float16*)(base + 24 * MB);   // [1024][1024]
    float*    Marr    = (float*)(base + 32 * MB);
    float*    Larr    = (float*)(base + 33 * MB);
    _Float16* CarrT   = (_Float16*)(base + 34 * MB);   // [64][4096]
    _Float16* Qh      = (_Float16*)(base + 64 * MB);   // [4096][1024]
    _Float16* Kh      = (_Float16*)(base + 72 * MB);   // [4096][1024]
    _Float16* VT      = (_Float16*)(base + 96 * MB);   // [1024][4096]

    // 1) fused prep (hi/lo splits — 3-product needs them)
    prep<<<4096, 256, 0, stream>>>(x, wq, wk, wv, x_hi, x_lo, wqkT_hi, wqkT_lo, wvT);

    // 2) QK projection, consolidated 3-product (48 MFMA/window, 32 K-tiles)
    dim3 gqk(2048 / 256, SEQ / 128);   // (8,32) — XCD = col-panel
    gemm_qkproj_dp<<<gqk, dim3(512), 0, stream>>>(x_hi, x_lo, wqkT_hi, wqkT_lo,
                                                  Qh, Kh);
    // V^T = wvT @ x_hi^T, modernized ring
    dim3 gvt(SEQ / 64, DMODEL / 128);  // (64,8) = 512 blocks, 2/CU
    gemm_vt_dp<<<gvt, 256, 0, stream>>>(wvT, x_hi, VT);

    // 3) scores + tile-softmax, tile 256x128 -> 512 blocks = 2 blocks/CU
    dim3 gs(SEQ / 128, SEQ / 256);     // (32,16)
    gemm_score_dp<<<gs, dim3(512), 0, stream>>>(Qh, Kh, P, Marr, Larr,
                                                1.0f / 32.0f);

    // 4) finalize coefficients only (no P traffic), coalesced writes
    compute_c<<<SEQ / 64, 256, 0, stream>>>(Marr, Larr, CarrT);

    // 5) out = sum_t c_t * (P_t @ V_t), 2-slot ring, 2 blocks/CU
    dim3 gpv(DMODEL / 128, SEQ / 128); // (8,32) — XCD = col-panel
    gemm_pv_dp<<<gpv, dim3(512), 0, stream>>>(P, VT, CarrT, out);
}